// Round 6
// baseline (744.127 us; speedup 1.0000x reference)
//
#include <hip/hip_runtime.h>
#include <hip/hip_fp16.h>
#include <math.h>
#include <stdint.h>
#include <type_traits>

#define NN   100000
#define EE   1200000
#define GG   128
#define FIN  16
#define HH   64
#define OUTF 5
#define NHID 3

#define CE   4096                       // edges per block in bucket phases
#define EB   ((EE + CE - 1) / CE)       // 293 edge-blocks
#define NBUK ((NN + 511) >> 9)          // 196 buckets of 512 nodes
#define LEN  (NBUK * EB)                // hblk/eoff length

#define SRCMASK 0x03FFFFFFu             // low 26 bits of packed col entry
#define FB_DST 32                       // dsts per fused block

typedef _Float16 f16x8 __attribute__((ext_vector_type(8)));
typedef _Float16 f16x2 __attribute__((ext_vector_type(2)));
typedef float f32x4 __attribute__((ext_vector_type(4)));

#if defined(__has_builtin)
#if __has_builtin(__builtin_amdgcn_fdot2)
#define HAVE_FDOT2 1
#endif
#endif

static __device__ __forceinline__ float dot8_acc(f16x8 a, f16x8 b, float ds) {
#ifdef HAVE_FDOT2
#pragma unroll
  for (int u = 0; u < 4; u++) {
    f16x2 x = {a[2 * u], a[2 * u + 1]};
    f16x2 y = {b[2 * u], b[2 * u + 1]};
    ds = __builtin_amdgcn_fdot2(x, y, ds, false);
  }
#else
#pragma unroll
  for (int u = 0; u < 8; u++) ds += (float)a[u] * (float)b[u];
#endif
  return ds;
}

// ---------------- wave helpers ----------------
static __device__ __forceinline__ float wave_reduce_sum(float p) {
#pragma unroll
  for (int m = 32; m >= 1; m >>= 1) p += __shfl_xor(p, m, 64);
  return p;
}

// ---------------- bucketed CSR build ----------------
__global__ void k_bh(const int* __restrict__ ei, int* __restrict__ hblk) {
  __shared__ int h[NBUK];
  int tid = threadIdx.x, blk = blockIdx.x;
  for (int i = tid; i < NBUK; i += 256) h[i] = 0;
  __syncthreads();
  int base = blk * CE;
  for (int i = tid; i < CE; i += 256) {
    int e = base + i;
    if (e < EE) atomicAdd(&h[ei[EE + e] >> 9], 1);
  }
  __syncthreads();
  for (int i = tid; i < NBUK; i += 256) hblk[i * EB + blk] = h[i];
}

__global__ void k_scan1(const int* __restrict__ in, int* __restrict__ incl,
                        int* __restrict__ bsum, int n) {
  __shared__ int sd[256];
  int t = threadIdx.x, blk = blockIdx.x;
  int base = blk * 1024 + t * 4;
  int v[4];
#pragma unroll
  for (int i = 0; i < 4; i++) v[i] = (base + i < n) ? in[base + i] : 0;
  int s = v[0] + v[1] + v[2] + v[3];
  sd[t] = s;
  __syncthreads();
  for (int off = 1; off < 256; off <<= 1) {
    int x = 0;
    if (t >= off) x = sd[t - off];
    __syncthreads();
    if (t >= off) sd[t] += x;
    __syncthreads();
  }
  int run = sd[t] - s;
#pragma unroll
  for (int i = 0; i < 4; i++) {
    run += v[i];
    if (base + i < n) incl[base + i] = run;
  }
  if (t == 255) bsum[blk] = sd[255];
}

__global__ void k_scan2(const int* __restrict__ bsum, int* __restrict__ boff, int nb) {
  if (threadIdx.x == 0 && blockIdx.x == 0) {
    int run = 0;
    for (int i = 0; i < nb; i++) { boff[i] = run; run += bsum[i]; }
  }
}

__global__ void k_eoff(const int* __restrict__ incl, const int* __restrict__ boff,
                       const int* __restrict__ hblk, int* __restrict__ eoff, int n) {
  int t = blockIdx.x * blockDim.x + threadIdx.x;
  if (t < n) eoff[t] = incl[t] + boff[t / 1024] - hblk[t];
}

__global__ void k_binwrite(const int* __restrict__ ei, const int* __restrict__ eoff,
                           int2* __restrict__ ebuf) {
  __shared__ int cur[NBUK];
  int tid = threadIdx.x, blk = blockIdx.x;
  for (int i = tid; i < NBUK; i += 256) cur[i] = eoff[i * EB + blk];
  __syncthreads();
  int base = blk * CE;
  for (int i = tid; i < CE; i += 256) {
    int e = base + i;
    if (e < EE) {
      int d = ei[EE + e];
      int s = ei[e];
      int p = atomicAdd(&cur[d >> 9], 1);
      ebuf[p] = make_int2(s, d);
    }
  }
}

// merged bdeg2 + binscatter: histogram -> scan -> row_ptr -> cursors ->
// scatter col. col entry packs dst-mod-64 into bits 26..31; src (<2^26)
// in low bits. Fused blocks are 64-grid-aligned (32 dsts), so dst-local
// decodes as (v>>26)&31.
__global__ void k_bcsr(const int2* __restrict__ ebuf, const int* __restrict__ eoff,
                       int* __restrict__ row_ptr, int* __restrict__ col, int n) {
  __shared__ int dl[512];
  __shared__ int ps[256];
  int b = blockIdx.x, tid = threadIdx.x;
  int d0 = b << 9;
  dl[tid] = 0; dl[tid + 256] = 0;
  __syncthreads();
  int s0 = eoff[b * EB];
  int s1 = (b + 1 < NBUK) ? eoff[(b + 1) * EB] : EE;
  for (int e = s0 + tid; e < s1; e += 256) atomicAdd(&dl[ebuf[e].y - d0], 1);
  __syncthreads();
  int a0 = dl[2 * tid], a1 = dl[2 * tid + 1];
  ps[tid] = a0 + a1;
  __syncthreads();
  for (int off = 1; off < 256; off <<= 1) {
    int x = 0;
    if (tid >= off) x = ps[tid - off];
    __syncthreads();
    if (tid >= off) ps[tid] += x;
    __syncthreads();
  }
  int epair = ps[tid] - (a0 + a1);     // exclusive prefix of this pair
  int r0 = s0 + epair;
  int r1 = r0 + a0;
  int i0 = d0 + 2 * tid;
  if (i0 <= n) row_ptr[i0] = r0;       // covers row_ptr[n] = EE
  if (i0 + 1 <= n) row_ptr[i0 + 1] = r1;
  __syncthreads();
  dl[2 * tid] = r0;                    // reuse histogram LDS as cursors
  dl[2 * tid + 1] = r1;
  __syncthreads();
  for (int e = s0 + tid; e < s1; e += 256) {
    int2 sd = ebuf[e];
    int p = atomicAdd(&dl[sd.y - d0], 1);
    col[p] = (int)(((unsigned)sd.x) | (((unsigned)sd.y & 63u) << 26));
  }
}

// ---------------- weight pre-pack (R21) ----------------
// Packs all 16 weight matrices into per-lane fragment order once per call:
// P[slot][lane][ (ns*KH+kh2)*8 + j ] = W[kidx*64 + ns*16 + (lane&15)],
// kidx = kh2*32 + (lane>>4)*8 + j (zero if >= F). Slot = 8KB (4096 halves).
// Kills the 64x strided scalar weight loads per lane in every GEMM block.
__global__ void k_wpack(const float* __restrict__ Wq0, const float* __restrict__ Wk0,
                        const float* __restrict__ Wv0, const float* __restrict__ Ws0,
                        const float* __restrict__ Wqh, const float* __restrict__ Wkh,
                        const float* __restrict__ Wvh, const float* __restrict__ Wsh,
                        __half* __restrict__ P) {
  int b = blockIdx.x, tid = threadIdx.x;
  const float* W; int F, KH;
  if (b < 4) {
    W = (b == 0) ? Wq0 : (b == 1) ? Wk0 : (b == 2) ? Wv0 : Ws0;
    F = 16; KH = 1;
  } else {
    int L = (b - 4) >> 2, m = (b - 4) & 3;
    const float* base = (m == 0) ? Wqh : (m == 1) ? Wkh : (m == 2) ? Wvh : Wsh;
    W = base + L * 4096;
    F = 64; KH = 2;
  }
  int PL = 4 * KH * 8;
  int total = 64 * PL;
  __half* Pb = P + b * 4096;
  for (int idx = tid; idx < total; idx += 256) {
    int lane = idx / PL, r = idx % PL;
    int ns = (r >> 3) / KH;
    int kh2 = (r >> 3) % KH;
    int j = r & 7;
    int kidx = kh2 * 32 + (lane >> 4) * 8 + j;
    float v = (kidx < F) ? W[kidx * 64 + ns * 16 + (lane & 15)] : 0.f;
    Pb[idx] = __float2half(v);
  }
}

// ---------------- projections via MFMA (packed weights) ----------------
template <int F, typename TIN>
__global__ __launch_bounds__(256) void k_gemm_mfma(
    const TIN* __restrict__ X,
    const __half* __restrict__ Pq, const __half* __restrict__ Pk,
    const __half* __restrict__ Pv, const __half* __restrict__ Ps,
    const float* __restrict__ bq, const float* __restrict__ bk,
    const float* __restrict__ bv, const float* __restrict__ bs,
    __half* __restrict__ qh, __half* __restrict__ kh, __half* __restrict__ vh,
    __half* __restrict__ Bh, int n) {
  constexpr int KH = (F + 31) / 32;
  constexpr int PL = 4 * KH * 8;
  constexpr int S = KH * 32 + 8;
  __shared__ _Float16 xs[64 * S];
  int tid = threadIdx.x;
  int lane = tid & 63;
  int wv = tid >> 6;
  int quad = lane >> 4;
  int li = lane & 15;
  int node0 = blockIdx.x * 64;

  if constexpr (std::is_same<TIN, float>::value) {
    constexpr int F4 = F / 4;
    constexpr int CNT = 64 * F4 / 256;
#pragma unroll
    for (int i = 0; i < CNT; i++) {
      int idx = tid + i * 256;
      int nd = idx / F4;
      int kb = (idx % F4) * 4;
      float4 p;
      if (node0 + nd < n) p = *(const float4*)(X + (size_t)(node0 + nd) * F + kb);
      else p = make_float4(0.f, 0.f, 0.f, 0.f);
      _Float16* d = xs + nd * S + kb;
      d[0] = (_Float16)p.x; d[1] = (_Float16)p.y;
      d[2] = (_Float16)p.z; d[3] = (_Float16)p.w;
    }
    if (F == 16) {  // zero-pad k in [16,32)
      int nd = tid >> 2;
      int kb = 16 + (tid & 3) * 4;
      _Float16* d = xs + nd * S + kb;
      d[0] = 0; d[1] = 0; d[2] = 0; d[3] = 0;
    }
  } else {
    constexpr int F8 = F / 8;
    constexpr int CNT = 64 * F8 / 256;
#pragma unroll
    for (int i = 0; i < CNT; i++) {
      int idx = tid + i * 256;
      int nd = idx / F8;
      int kb = (idx % F8) * 8;
      f16x8 p = {};
      if (node0 + nd < n)
        p = *(const f16x8*)((const _Float16*)X + (size_t)(node0 + nd) * F + kb);
      *(f16x8*)(xs + nd * S + kb) = p;
    }
  }

  const __half* Pm; const float* bias;
  if (wv == 0)      { Pm = Pq; bias = bq; }
  else if (wv == 1) { Pm = Pk; bias = bk; }
  else if (wv == 2) { Pm = Pv; bias = bv; }
  else              { Pm = Ps; bias = bs; }

  const _Float16* pw = (const _Float16*)Pm + lane * PL;
  f16x8 bf[4][KH];
#pragma unroll
  for (int ns = 0; ns < 4; ns++)
#pragma unroll
    for (int kh2 = 0; kh2 < KH; kh2++)
      bf[ns][kh2] = *(const f16x8*)(pw + (ns * KH + kh2) * 8);
  float blv[4];
#pragma unroll
  for (int ns = 0; ns < 4; ns++) blv[ns] = bias[ns * 16 + li];

  __syncthreads();

  f16x8 af[4][KH];
#pragma unroll
  for (int ms = 0; ms < 4; ms++)
#pragma unroll
    for (int kh2 = 0; kh2 < KH; kh2++)
      af[ms][kh2] = *(const f16x8*)(xs + (ms * 16 + li) * S + kh2 * 32 + quad * 8);

  f32x4 acc[4][4];
#pragma unroll
  for (int ms = 0; ms < 4; ms++)
#pragma unroll
    for (int ns = 0; ns < 4; ns++) {
      float b = blv[ns];
      acc[ms][ns] = (f32x4){b, b, b, b};
    }
#pragma unroll
  for (int kh2 = 0; kh2 < KH; kh2++)
#pragma unroll
    for (int ms = 0; ms < 4; ms++)
#pragma unroll
      for (int ns = 0; ns < 4; ns++)
        acc[ms][ns] = __builtin_amdgcn_mfma_f32_16x16x32_f16(
            af[ms][kh2], bf[ns][kh2], acc[ms][ns], 0, 0, 0);

  __half* outh = (wv == 0) ? qh : (wv == 1) ? kh : (wv == 2) ? vh : Bh;
#pragma unroll
  for (int ms = 0; ms < 4; ms++)
#pragma unroll
    for (int ns = 0; ns < 4; ns++) {
      int colc = ns * 16 + li;
#pragma unroll
      for (int r = 0; r < 4; r++) {
        int node = node0 + ms * 16 + quad * 4 + r;
        if (node < n)
          outh[(size_t)node * 64 + colc] = __float2half(acc[ms][ns][r]);
      }
    }
}

// ---------------- fused attention (R21) ----------------
// Block = 32 consecutive dsts, 128 threads. Phase A: EACH LANE OWNS ONE
// EDGE — q row from LDS (stride-68 pad, <=2-way bank alias), per-lane
// 8x b128 k-row gather, 32 fdot2, NO cross-lane ops (R20's 3 dependent
// ds_bpermute per edge were the critical path). Manual x2 edge unroll
// for deeper MLP. Phase B unchanged: 4 groups x 32 lanes, register
// accumulators, coalesced v rows.
__global__ __launch_bounds__(128) void k_fused(
    const __half* __restrict__ qh, const __half* __restrict__ kh,
    const __half* __restrict__ vh, const int* __restrict__ row_ptr,
    const int* __restrict__ col, __half* __restrict__ Bh, int n) {
  __shared__ int2 ws[512];             // .x = packed col, .y = weight bits
  __shared__ _Float16 qs[32 * 68];     // q rows, stride 68 halves
  __shared__ int rpl[FB_DST + 1];
  int tid = threadIdx.x;
  int d0 = blockIdx.x * FB_DST;
  int ndst = n - d0; if (ndst > FB_DST) ndst = FB_DST;

  if (tid < FB_DST + 1) {
    int dd = d0 + tid; if (dd > n) dd = n;
    rpl[tid] = row_ptr[dd];
  }
  // stage q rows: 256 16B-chunks, coalesced
#pragma unroll
  for (int s = 0; s < 2; s++) {
    int c = tid + s * 128;
    int row = c >> 3, j = c & 7;
    f16x8 v = {};
    if (row < ndst)
      v = *(const f16x8*)((const _Float16*)qh + (size_t)(d0 + row) * 64 + j * 8);
    *(f16x8*)(qs + row * 68 + j * 8) = v;
  }
  __syncthreads();
  int e0 = rpl[0], e1 = rpl[ndst];

  int gid = tid >> 5, hl = tid & 31;   // phase B: 4 groups x 32 lanes

  float2 acc[8];
  float den[8];
#pragma unroll
  for (int k = 0; k < 8; k++) { acc[k] = make_float2(0.f, 0.f); den[k] = 0.f; }

  for (int c0 = e0; c0 < e1; c0 += 512) {
    int cn = e1 - c0; if (cn > 512) cn = 512;
    // stage col chunk (coalesced)
#pragma unroll
    for (int s = 0; s < 4; s++) {
      int i = tid + s * 128;
      if (i < cn) ws[i].x = col[c0 + i];
    }
    __syncthreads();

    // ---- phase A: per-lane edges, x2 unroll ----
    {
      int i = tid;
      for (; i + 128 < cn; i += 256) {
        unsigned v0 = (unsigned)ws[i].x;
        unsigned v1 = (unsigned)ws[i + 128].x;
        const _Float16* k0 = (const _Float16*)kh + (size_t)(v0 & SRCMASK) * 64;
        const _Float16* k1 = (const _Float16*)kh + (size_t)(v1 & SRCMASK) * 64;
        const _Float16* q0 = qs + ((v0 >> 26) & 31u) * 68;
        const _Float16* q1 = qs + ((v1 >> 26) & 31u) * 68;
        float da = 0.f, db = 0.f;
#pragma unroll
        for (int c = 0; c < 8; c++) {
          f16x8 ka = *(const f16x8*)(k0 + c * 8);
          f16x8 qa = *(const f16x8*)(q0 + c * 8);
          f16x8 kb = *(const f16x8*)(k1 + c * 8);
          f16x8 qb = *(const f16x8*)(q1 + c * 8);
          da = dot8_acc(qa, ka, da);
          db = dot8_acc(qb, kb, db);
        }
        ws[i].y       = __float_as_int(__expf(fminf(da * 0.125f, 60.f)));
        ws[i + 128].y = __float_as_int(__expf(fminf(db * 0.125f, 60.f)));
      }
      if (i < cn) {
        unsigned v0 = (unsigned)ws[i].x;
        const _Float16* k0 = (const _Float16*)kh + (size_t)(v0 & SRCMASK) * 64;
        const _Float16* q0 = qs + ((v0 >> 26) & 31u) * 68;
        float da = 0.f;
#pragma unroll
        for (int c = 0; c < 8; c++) {
          f16x8 ka = *(const f16x8*)(k0 + c * 8);
          f16x8 qa = *(const f16x8*)(q0 + c * 8);
          da = dot8_acc(qa, ka, da);
        }
        ws[i].y = __float_as_int(__expf(fminf(da * 0.125f, 60.f)));
      }
    }
    __syncthreads();

    // ---- phase B: aggregate; group gid owns dsts gid*8 .. gid*8+7 ----
#pragma unroll
    for (int k = 0; k < 8; k++) {
      int dl = gid * 8 + k;
      if (dl < ndst) {
        int lo2 = rpl[dl];     if (lo2 < c0) lo2 = c0;
        int hi2 = rpl[dl + 1]; if (hi2 > c0 + cn) hi2 = c0 + cn;
        int i = lo2 - c0, iend = hi2 - c0;
        for (; i + 2 <= iend; i += 2) {
          int2 p0 = ws[i], p1 = ws[i + 1];
          float w0 = __int_as_float(p0.y); int s0 = p0.x & (int)SRCMASK;
          float w1 = __int_as_float(p1.y); int s1 = p1.x & (int)SRCMASK;
          float2 f0 = __half22float2(*(const __half2*)(vh + (size_t)s0 * 64 + hl * 2));
          float2 f1 = __half22float2(*(const __half2*)(vh + (size_t)s1 * 64 + hl * 2));
          acc[k].x = fmaf(w0, f0.x, acc[k].x); acc[k].y = fmaf(w0, f0.y, acc[k].y);
          acc[k].x = fmaf(w1, f1.x, acc[k].x); acc[k].y = fmaf(w1, f1.y, acc[k].y);
          den[k] += w0 + w1;
        }
        if (i < iend) {
          int2 p0 = ws[i];
          float w0 = __int_as_float(p0.y); int s0 = p0.x & (int)SRCMASK;
          float2 f0 = __half22float2(*(const __half2*)(vh + (size_t)s0 * 64 + hl * 2));
          acc[k].x = fmaf(w0, f0.x, acc[k].x); acc[k].y = fmaf(w0, f0.y, acc[k].y);
          den[k] += w0;
        }
      }
    }
    __syncthreads();   // before next chunk overwrites ws
  }

  // write out (B pre-holds the skip term)
#pragma unroll
  for (int k = 0; k < 8; k++) {
    int dl = gid * 8 + k;
    if (dl < ndst) {
      __half2* bp = (__half2*)(Bh + (size_t)(d0 + dl) * 64) + hl;
      float2 old = __half22float2(*bp);
      float inv = 1.f / (den[k] + 1e-16f);
      old.x += acc[k].x * inv;
      old.y += acc[k].y * inv;
      *bp = __float22half2_rn(old);
    }
  }
}

// ---------------- pooling ----------------
__global__ __launch_bounds__(256) void k_pool(
    const __half* __restrict__ H, const int* __restrict__ batch,
    float* __restrict__ pooled, int* __restrict__ cnt, int n) {
  int lane = threadIdx.x & 63;
  int w = threadIdx.x >> 6;
  int n0 = blockIdx.x * 64 + w * 16;
  float acc = 0.f;
  int cur = -1, nc = 0;
  for (int i = 0; i < 16; i++) {
    int node = n0 + i;
    if (node >= n) break;
    int g = batch[node];
    if (g != cur) {
      if (cur >= 0) {
        atomicAdd(&pooled[cur * 64 + lane], acc);
        if (lane == 0) atomicAdd(&cnt[cur], nc);
      }
      cur = g;
      acc = 0.f;
      nc = 0;
    }
    acc += __half2float(H[(size_t)node * 64 + lane]);
    nc++;
  }
  if (cur >= 0) {
    atomicAdd(&pooled[cur * 64 + lane], acc);
    if (lane == 0) atomicAdd(&cnt[cur], nc);
  }
}

__global__ void k_out(const float* __restrict__ pooled, const int* __restrict__ cnt,
                      const float* __restrict__ Wf, const float* __restrict__ bf,
                      float* __restrict__ out) {
  int g = blockIdx.x;
  int lane = threadIdx.x;
  int c = cnt[g];
  float cf = (float)(c > 1 ? c : 1);
  float mean = pooled[g * 64 + lane] / cf;
#pragma unroll
  for (int o = 0; o < OUTF; o++) {
    float p = wave_reduce_sum(mean * Wf[lane * OUTF + o]);
    if (lane == 0) out[g * OUTF + o] = p + bf[o];
  }
}

// ---------------- launch ----------------
extern "C" void kernel_launch(void* const* d_in, const int* in_sizes, int n_in,
                              void* d_out, int out_size, void* d_ws, size_t ws_size,
                              hipStream_t stream) {
  const float* x   = (const float*)d_in[0];
  const int* ei    = (const int*)d_in[1];
  const int* batch = (const int*)d_in[2];
  const float *Wq0 = (const float*)d_in[3],  *bq0 = (const float*)d_in[4];
  const float *Wk0 = (const float*)d_in[5],  *bk0 = (const float*)d_in[6];
  const float *Wv0 = (const float*)d_in[7],  *bv0 = (const float*)d_in[8];
  const float *Ws0 = (const float*)d_in[9],  *bs0 = (const float*)d_in[10];
  const float *Wqh = (const float*)d_in[11], *bqh = (const float*)d_in[12];
  const float *Wkh = (const float*)d_in[13], *bkh = (const float*)d_in[14];
  const float *Wvh = (const float*)d_in[15], *bvh = (const float*)d_in[16];
  const float *Wsh = (const float*)d_in[17], *bsh = (const float*)d_in[18];
  const float *Wf  = (const float*)d_in[19], *bf  = (const float*)d_in[20];

  __half* qh = (__half*)d_ws;
  __half* kh = qh + (size_t)NN * 64;
  __half* vh = kh + (size_t)NN * 64;
  __half* B0 = vh + (size_t)NN * 64;
  __half* B1 = B0 + (size_t)NN * 64;
  float* pooled = (float*)(B1 + (size_t)NN * 64);
  int* cnt     = (int*)(pooled + GG * 64);
  int* row_ptr = cnt + GG;
  int* col     = row_ptr + NN + 2;
  int* hblk    = col + EE;
  int* incl2   = hblk + LEN;
  int* bsum2   = incl2 + LEN;
  int* boff2   = bsum2 + 128;
  int* eoff    = boff2 + 128;
  int2* ebuf   = (int2*)((((uintptr_t)(eoff + LEN)) + 15) & ~(uintptr_t)15);
  __half* Pall = (__half*)(ebuf + EE);   // 16 slots x 4096 halves = 128KB

  hipMemsetAsync(pooled, 0, (GG * 64 + GG) * sizeof(float), stream);

  // weight pre-pack (once per call; all 16 matrices)
  k_wpack<<<16, 256, 0, stream>>>(Wq0, Wk0, Wv0, Ws0, Wqh, Wkh, Wvh, Wsh, Pall);

  // bucketed CSR build (once per call; reused by all 4 layers)
  k_bh<<<EB, 256, 0, stream>>>(ei, hblk);
  int nb2 = (LEN + 1023) / 1024;
  k_scan1<<<nb2, 256, 0, stream>>>(hblk, incl2, bsum2, LEN);
  k_scan2<<<1, 64, 0, stream>>>(bsum2, boff2, nb2);
  k_eoff<<<(LEN + 255) / 256, 256, 0, stream>>>(incl2, boff2, hblk, eoff, LEN);
  k_binwrite<<<EB, 256, 0, stream>>>(ei, eoff, ebuf);
  k_bcsr<<<NBUK, 256, 0, stream>>>(ebuf, eoff, row_ptr, col, NN);

  int gg = (NN + 63) / 64;
  int ga = (NN + FB_DST - 1) / FB_DST;  // 32 dsts per block, 128 threads

  // layer 0 (F_IN=16, fp32 input)
  k_gemm_mfma<FIN, float><<<gg, 256, 0, stream>>>(
      x, Pall, Pall + 4096, Pall + 2 * 4096, Pall + 3 * 4096,
      bq0, bk0, bv0, bs0, qh, kh, vh, B0, NN);
  k_fused<<<ga, 128, 0, stream>>>(qh, kh, vh, row_ptr, col, B0, NN);

  // hidden layers (H=64, fp16 h), ping-pong B0 <-> B1
  const __half* hin = B0;
  __half* hout = B1;
  for (int i = 0; i < NHID; i++) {
    const __half* Pb = Pall + (size_t)(4 + i * 4) * 4096;
    k_gemm_mfma<HH, __half><<<gg, 256, 0, stream>>>(
        hin, Pb, Pb + 4096, Pb + 2 * 4096, Pb + 3 * 4096,
        bqh + i * 64, bkh + i * 64, bvh + i * 64, bsh + i * 64,
        qh, kh, vh, hout, NN);
    k_fused<<<ga, 128, 0, stream>>>(qh, kh, vh, row_ptr, col, hout, NN);
    __half* t = (__half*)hin; hin = hout; hout = t;
  }

  k_pool<<<(NN + 63) / 64, 256, 0, stream>>>(hin, batch, pooled, cnt, NN);
  k_out<<<GG, 64, 0, stream>>>(pooled, cnt, Wf, bf, (float*)d_out);
}

// Round 7
// 483.220 us; speedup vs baseline: 1.5399x; 1.5399x over previous
//
#include <hip/hip_runtime.h>
#include <hip/hip_fp16.h>
#include <math.h>
#include <stdint.h>
#include <type_traits>

#define NN   100000
#define EE   1200000
#define GG   128
#define FIN  16
#define HH   64
#define OUTF 5
#define NHID 3

#define CE   4096                       // edges per block in bucket phases
#define EB   ((EE + CE - 1) / CE)       // 293 edge-blocks
#define NBUK ((NN + 511) >> 9)          // 196 buckets of 512 nodes
#define LEN  (NBUK * EB)                // hblk/eoff length

#define SRCMASK 0x03FFFFFFu             // low 26 bits of packed col entry
#define FB_DST 32                       // dsts per fused block

typedef _Float16 f16x8 __attribute__((ext_vector_type(8)));
typedef _Float16 f16x2 __attribute__((ext_vector_type(2)));
typedef float f32x4 __attribute__((ext_vector_type(4)));

#if defined(__has_builtin)
#if __has_builtin(__builtin_amdgcn_fdot2)
#define HAVE_FDOT2 1
#endif
#endif

static __device__ __forceinline__ float dot8_f16(f16x8 a, f16x8 b) {
#ifdef HAVE_FDOT2
  float ds = 0.f;
#pragma unroll
  for (int u = 0; u < 4; u++) {
    f16x2 x = {a[2 * u], a[2 * u + 1]};
    f16x2 y = {b[2 * u], b[2 * u + 1]};
    ds = __builtin_amdgcn_fdot2(x, y, ds, false);
  }
  return ds;
#else
  float ds = 0.f;
#pragma unroll
  for (int u = 0; u < 8; u++) ds += (float)a[u] * (float)b[u];
  return ds;
#endif
}

// ---------------- wave helpers ----------------
static __device__ __forceinline__ float wave_reduce_sum(float p) {
#pragma unroll
  for (int m = 32; m >= 1; m >>= 1) p += __shfl_xor(p, m, 64);
  return p;
}

// ---------------- bucketed CSR build ----------------
__global__ void k_bh(const int* __restrict__ ei, int* __restrict__ hblk) {
  __shared__ int h[NBUK];
  int tid = threadIdx.x, blk = blockIdx.x;
  for (int i = tid; i < NBUK; i += 256) h[i] = 0;
  __syncthreads();
  int base = blk * CE;
  for (int i = tid; i < CE; i += 256) {
    int e = base + i;
    if (e < EE) atomicAdd(&h[ei[EE + e] >> 9], 1);
  }
  __syncthreads();
  for (int i = tid; i < NBUK; i += 256) hblk[i * EB + blk] = h[i];
}

__global__ void k_scan1(const int* __restrict__ in, int* __restrict__ incl,
                        int* __restrict__ bsum, int n) {
  __shared__ int sd[256];
  int t = threadIdx.x, blk = blockIdx.x;
  int base = blk * 1024 + t * 4;
  int v[4];
#pragma unroll
  for (int i = 0; i < 4; i++) v[i] = (base + i < n) ? in[base + i] : 0;
  int s = v[0] + v[1] + v[2] + v[3];
  sd[t] = s;
  __syncthreads();
  for (int off = 1; off < 256; off <<= 1) {
    int x = 0;
    if (t >= off) x = sd[t - off];
    __syncthreads();
    if (t >= off) sd[t] += x;
    __syncthreads();
  }
  int run = sd[t] - s;
#pragma unroll
  for (int i = 0; i < 4; i++) {
    run += v[i];
    if (base + i < n) incl[base + i] = run;
  }
  if (t == 255) bsum[blk] = sd[255];
}

__global__ void k_scan2(const int* __restrict__ bsum, int* __restrict__ boff, int nb) {
  if (threadIdx.x == 0 && blockIdx.x == 0) {
    int run = 0;
    for (int i = 0; i < nb; i++) { boff[i] = run; run += bsum[i]; }
  }
}

__global__ void k_eoff(const int* __restrict__ incl, const int* __restrict__ boff,
                       const int* __restrict__ hblk, int* __restrict__ eoff, int n) {
  int t = blockIdx.x * blockDim.x + threadIdx.x;
  if (t < n) eoff[t] = incl[t] + boff[t / 1024] - hblk[t];
}

__global__ void k_binwrite(const int* __restrict__ ei, const int* __restrict__ eoff,
                           int2* __restrict__ ebuf) {
  __shared__ int cur[NBUK];
  int tid = threadIdx.x, blk = blockIdx.x;
  for (int i = tid; i < NBUK; i += 256) cur[i] = eoff[i * EB + blk];
  __syncthreads();
  int base = blk * CE;
  for (int i = tid; i < CE; i += 256) {
    int e = base + i;
    if (e < EE) {
      int d = ei[EE + e];
      int s = ei[e];
      int p = atomicAdd(&cur[d >> 9], 1);
      ebuf[p] = make_int2(s, d);
    }
  }
}

// merged bdeg2 + binscatter: histogram -> scan -> row_ptr -> cursors ->
// scatter col. col entry packs dst-mod-64 into bits 26..31; src (<2^26)
// in low bits. Fused blocks are 64-grid-aligned (32 dsts), so dst-local
// decodes as (v>>26)&31.
__global__ void k_bcsr(const int2* __restrict__ ebuf, const int* __restrict__ eoff,
                       int* __restrict__ row_ptr, int* __restrict__ col, int n) {
  __shared__ int dl[512];
  __shared__ int ps[256];
  int b = blockIdx.x, tid = threadIdx.x;
  int d0 = b << 9;
  dl[tid] = 0; dl[tid + 256] = 0;
  __syncthreads();
  int s0 = eoff[b * EB];
  int s1 = (b + 1 < NBUK) ? eoff[(b + 1) * EB] : EE;
  for (int e = s0 + tid; e < s1; e += 256) atomicAdd(&dl[ebuf[e].y - d0], 1);
  __syncthreads();
  int a0 = dl[2 * tid], a1 = dl[2 * tid + 1];
  ps[tid] = a0 + a1;
  __syncthreads();
  for (int off = 1; off < 256; off <<= 1) {
    int x = 0;
    if (tid >= off) x = ps[tid - off];
    __syncthreads();
    if (tid >= off) ps[tid] += x;
    __syncthreads();
  }
  int epair = ps[tid] - (a0 + a1);     // exclusive prefix of this pair
  int r0 = s0 + epair;
  int r1 = r0 + a0;
  int i0 = d0 + 2 * tid;
  if (i0 <= n) row_ptr[i0] = r0;       // covers row_ptr[n] = EE
  if (i0 + 1 <= n) row_ptr[i0 + 1] = r1;
  __syncthreads();
  dl[2 * tid] = r0;                    // reuse histogram LDS as cursors
  dl[2 * tid + 1] = r1;
  __syncthreads();
  for (int e = s0 + tid; e < s1; e += 256) {
    int2 sd = ebuf[e];
    int p = atomicAdd(&dl[sd.y - d0], 1);
    col[p] = (int)(((unsigned)sd.x) | (((unsigned)sd.y & 63u) << 26));
  }
}

// ---------------- weight pre-pack ----------------
// Packs all 16 weight matrices into per-lane fragment order once per call.
__global__ void k_wpack(const float* __restrict__ Wq0, const float* __restrict__ Wk0,
                        const float* __restrict__ Wv0, const float* __restrict__ Ws0,
                        const float* __restrict__ Wqh, const float* __restrict__ Wkh,
                        const float* __restrict__ Wvh, const float* __restrict__ Wsh,
                        __half* __restrict__ P) {
  int b = blockIdx.x, tid = threadIdx.x;
  const float* W; int F, KH;
  if (b < 4) {
    W = (b == 0) ? Wq0 : (b == 1) ? Wk0 : (b == 2) ? Wv0 : Ws0;
    F = 16; KH = 1;
  } else {
    int L = (b - 4) >> 2, m = (b - 4) & 3;
    const float* base = (m == 0) ? Wqh : (m == 1) ? Wkh : (m == 2) ? Wvh : Wsh;
    W = base + L * 4096;
    F = 64; KH = 2;
  }
  int PL = 4 * KH * 8;
  int total = 64 * PL;
  __half* Pb = P + b * 4096;
  for (int idx = tid; idx < total; idx += 256) {
    int lane = idx / PL, r = idx % PL;
    int ns = (r >> 3) / KH;
    int kh2 = (r >> 3) % KH;
    int j = r & 7;
    int kidx = kh2 * 32 + (lane >> 4) * 8 + j;
    float v = (kidx < F) ? W[kidx * 64 + ns * 16 + (lane & 15)] : 0.f;
    Pb[idx] = __float2half(v);
  }
}

// ---------------- projections via MFMA (packed weights, R22 epilogue) -------
// R22: LDS-staged coalesced stores. After MFMA, waves round-robin the dead
// xs buffer: write 64x64 acc tile (stride 68 vs bank alias), read back as
// f16x8, store 1KB fully-contiguous per instruction (8 nodes x 128B).
// Replaces 64x scalar 2B stores/lane (4x32B scattered fragments per instr).
template <int F, typename TIN>
__global__ __launch_bounds__(256) void k_gemm_mfma(
    const TIN* __restrict__ X,
    const __half* __restrict__ Pq, const __half* __restrict__ Pk,
    const __half* __restrict__ Pv, const __half* __restrict__ Ps,
    const float* __restrict__ bq, const float* __restrict__ bk,
    const float* __restrict__ bv, const float* __restrict__ bs,
    __half* __restrict__ qh, __half* __restrict__ kh, __half* __restrict__ vh,
    __half* __restrict__ Bh, int n) {
  constexpr int KH = (F + 31) / 32;
  constexpr int PL = 4 * KH * 8;
  constexpr int S = KH * 32 + 8;
  constexpr int SB = (S > 68) ? S : 68;   // buffer serves x-stage AND out-stage
  __shared__ _Float16 xs[64 * SB];
  int tid = threadIdx.x;
  int lane = tid & 63;
  int wv = tid >> 6;
  int quad = lane >> 4;
  int li = lane & 15;
  int node0 = blockIdx.x * 64;

  if constexpr (std::is_same<TIN, float>::value) {
    constexpr int F4 = F / 4;
    constexpr int CNT = 64 * F4 / 256;
#pragma unroll
    for (int i = 0; i < CNT; i++) {
      int idx = tid + i * 256;
      int nd = idx / F4;
      int kb = (idx % F4) * 4;
      float4 p;
      if (node0 + nd < n) p = *(const float4*)(X + (size_t)(node0 + nd) * F + kb);
      else p = make_float4(0.f, 0.f, 0.f, 0.f);
      _Float16* d = xs + nd * S + kb;
      d[0] = (_Float16)p.x; d[1] = (_Float16)p.y;
      d[2] = (_Float16)p.z; d[3] = (_Float16)p.w;
    }
    if (F == 16) {  // zero-pad k in [16,32)
      int nd = tid >> 2;
      int kb = 16 + (tid & 3) * 4;
      _Float16* d = xs + nd * S + kb;
      d[0] = 0; d[1] = 0; d[2] = 0; d[3] = 0;
    }
  } else {
    constexpr int F8 = F / 8;
    constexpr int CNT = 64 * F8 / 256;
#pragma unroll
    for (int i = 0; i < CNT; i++) {
      int idx = tid + i * 256;
      int nd = idx / F8;
      int kb = (idx % F8) * 8;
      f16x8 p = {};
      if (node0 + nd < n)
        p = *(const f16x8*)((const _Float16*)X + (size_t)(node0 + nd) * F + kb);
      *(f16x8*)(xs + nd * S + kb) = p;
    }
  }

  const __half* Pm; const float* bias;
  if (wv == 0)      { Pm = Pq; bias = bq; }
  else if (wv == 1) { Pm = Pk; bias = bk; }
  else if (wv == 2) { Pm = Pv; bias = bv; }
  else              { Pm = Ps; bias = bs; }

  const _Float16* pw = (const _Float16*)Pm + lane * PL;
  f16x8 bf[4][KH];
#pragma unroll
  for (int ns = 0; ns < 4; ns++)
#pragma unroll
    for (int kh2 = 0; kh2 < KH; kh2++)
      bf[ns][kh2] = *(const f16x8*)(pw + (ns * KH + kh2) * 8);
  float blv[4];
#pragma unroll
  for (int ns = 0; ns < 4; ns++) blv[ns] = bias[ns * 16 + li];

  __syncthreads();

  f16x8 af[4][KH];
#pragma unroll
  for (int ms = 0; ms < 4; ms++)
#pragma unroll
    for (int kh2 = 0; kh2 < KH; kh2++)
      af[ms][kh2] = *(const f16x8*)(xs + (ms * 16 + li) * S + kh2 * 32 + quad * 8);

  f32x4 acc[4][4];
#pragma unroll
  for (int ms = 0; ms < 4; ms++)
#pragma unroll
    for (int ns = 0; ns < 4; ns++) {
      float b = blv[ns];
      acc[ms][ns] = (f32x4){b, b, b, b};
    }
#pragma unroll
  for (int kh2 = 0; kh2 < KH; kh2++)
#pragma unroll
    for (int ms = 0; ms < 4; ms++)
#pragma unroll
      for (int ns = 0; ns < 4; ns++)
        acc[ms][ns] = __builtin_amdgcn_mfma_f32_16x16x32_f16(
            af[ms][kh2], bf[ns][kh2], acc[ms][ns], 0, 0, 0);

  __syncthreads();   // all xs reads complete before reuse as out-stage

#pragma unroll
  for (int w = 0; w < 4; w++) {
    if (wv == w) {
#pragma unroll
      for (int ms = 0; ms < 4; ms++)
#pragma unroll
        for (int ns = 0; ns < 4; ns++)
#pragma unroll
          for (int r = 0; r < 4; r++)
            xs[(ms * 16 + quad * 4 + r) * 68 + ns * 16 + li] =
                (_Float16)acc[ms][ns][r];
    }
    __syncthreads();
    if (wv == w) {
      __half* outh = (w == 0) ? qh : (w == 1) ? kh : (w == 2) ? vh : Bh;
#pragma unroll
      for (int it = 0; it < 8; it++) {
        int c = lane + it * 64;
        int row = c >> 3, j = c & 7;
        int node = node0 + row;
        if (node < n)
          *(f16x8*)((_Float16*)outh + (size_t)node * 64 + j * 8) =
              *(const f16x8*)(xs + row * 68 + j * 8);
      }
    }
    __syncthreads();
  }
}

// ---------------- fused attention (R20-proven) ----------------
// Block = 32 consecutive dsts, 128 threads. Phase A: 16 groups x 8 lanes,
// 8-lane cooperative k-row gather (one 128B coalesced transaction/row),
// dst-local from col bits 26..31, fdot2 dot, 3 shfl reduce, exp -> ws.y;
// x2 unroll. Phase B: 4 groups x 32 lanes, 8 dsts each, register
// accumulators, coalesced v rows, one b64 LDS read per edge.
__global__ __launch_bounds__(128) void k_fused(
    const __half* __restrict__ qh, const __half* __restrict__ kh,
    const __half* __restrict__ vh, const int* __restrict__ row_ptr,
    const int* __restrict__ col, __half* __restrict__ Bh, int n) {
  __shared__ int2 ws[512];             // .x = packed col, .y = weight bits
  __shared__ int rpl[FB_DST + 1];
  int tid = threadIdx.x;
  int d0 = blockIdx.x * FB_DST;
  int ndst = n - d0; if (ndst > FB_DST) ndst = FB_DST;

  if (tid < FB_DST + 1) {
    int dd = d0 + tid; if (dd > n) dd = n;
    rpl[tid] = row_ptr[dd];
  }
  __syncthreads();
  int e0 = rpl[0], e1 = rpl[ndst];

  int gid = tid >> 5, hl = tid & 31;   // phase B: 4 groups x 32 lanes
  int ag = tid >> 3, aj = tid & 7;     // phase A: 16 groups x 8 lanes

  float2 acc[8];
  float den[8];
#pragma unroll
  for (int k = 0; k < 8; k++) { acc[k] = make_float2(0.f, 0.f); den[k] = 0.f; }

  for (int c0 = e0; c0 < e1; c0 += 512) {
    int cn = e1 - c0; if (cn > 512) cn = 512;
    // stage col chunk (coalesced)
#pragma unroll
    for (int s = 0; s < 4; s++) {
      int i = tid + s * 128;
      if (i < cn) ws[i].x = col[c0 + i];
    }
    __syncthreads();

    // ---- phase A: scores (unrolled x2 per group) ----
    {
      int i = ag;
      for (; i + 16 < cn; i += 32) {
        unsigned v0 = (unsigned)ws[i].x;
        unsigned v1 = (unsigned)ws[i + 16].x;
        int src0 = (int)(v0 & SRCMASK), dl0 = (int)((v0 >> 26) & 31u);
        int src1 = (int)(v1 & SRCMASK), dl1 = (int)((v1 >> 26) & 31u);
        f16x8 kv0 = *(const f16x8*)((const _Float16*)kh + (size_t)src0 * 64 + aj * 8);
        f16x8 qv0 = *(const f16x8*)((const _Float16*)qh + (size_t)(d0 + dl0) * 64 + aj * 8);
        f16x8 kv1 = *(const f16x8*)((const _Float16*)kh + (size_t)src1 * 64 + aj * 8);
        f16x8 qv1 = *(const f16x8*)((const _Float16*)qh + (size_t)(d0 + dl1) * 64 + aj * 8);
        float ds0 = dot8_f16(qv0, kv0);
        float ds1 = dot8_f16(qv1, kv1);
        ds0 += __shfl_xor(ds0, 1, 64); ds1 += __shfl_xor(ds1, 1, 64);
        ds0 += __shfl_xor(ds0, 2, 64); ds1 += __shfl_xor(ds1, 2, 64);
        ds0 += __shfl_xor(ds0, 4, 64); ds1 += __shfl_xor(ds1, 4, 64);
        if (aj == 0) {
          ws[i].y      = __float_as_int(__expf(fminf(ds0 * 0.125f, 60.f)));
          ws[i + 16].y = __float_as_int(__expf(fminf(ds1 * 0.125f, 60.f)));
        }
      }
      if (i < cn) {
        unsigned v0 = (unsigned)ws[i].x;
        int src0 = (int)(v0 & SRCMASK), dl0 = (int)((v0 >> 26) & 31u);
        f16x8 kv0 = *(const f16x8*)((const _Float16*)kh + (size_t)src0 * 64 + aj * 8);
        f16x8 qv0 = *(const f16x8*)((const _Float16*)qh + (size_t)(d0 + dl0) * 64 + aj * 8);
        float ds0 = dot8_f16(qv0, kv0);
        ds0 += __shfl_xor(ds0, 1, 64);
        ds0 += __shfl_xor(ds0, 2, 64);
        ds0 += __shfl_xor(ds0, 4, 64);
        if (aj == 0) ws[i].y = __float_as_int(__expf(fminf(ds0 * 0.125f, 60.f)));
      }
    }
    __syncthreads();

    // ---- phase B: aggregate; group gid owns dsts gid*8 .. gid*8+7 ----
#pragma unroll
    for (int k = 0; k < 8; k++) {
      int dl = gid * 8 + k;
      if (dl < ndst) {
        int lo2 = rpl[dl];     if (lo2 < c0) lo2 = c0;
        int hi2 = rpl[dl + 1]; if (hi2 > c0 + cn) hi2 = c0 + cn;
        int i = lo2 - c0, iend = hi2 - c0;
        for (; i + 2 <= iend; i += 2) {
          int2 p0 = ws[i], p1 = ws[i + 1];
          float w0 = __int_as_float(p0.y); int s0 = p0.x & (int)SRCMASK;
          float w1 = __int_as_float(p1.y); int s1 = p1.x & (int)SRCMASK;
          float2 f0 = __half22float2(*(const __half2*)(vh + (size_t)s0 * 64 + hl * 2));
          float2 f1 = __half22float2(*(const __half2*)(vh + (size_t)s1 * 64 + hl * 2));
          acc[k].x = fmaf(w0, f0.x, acc[k].x); acc[k].y = fmaf(w0, f0.y, acc[k].y);
          acc[k].x = fmaf(w1, f1.x, acc[k].x); acc[k].y = fmaf(w1, f1.y, acc[k].y);
          den[k] += w0 + w1;
        }
        if (i < iend) {
          int2 p0 = ws[i];
          float w0 = __int_as_float(p0.y); int s0 = p0.x & (int)SRCMASK;
          float2 f0 = __half22float2(*(const __half2*)(vh + (size_t)s0 * 64 + hl * 2));
          acc[k].x = fmaf(w0, f0.x, acc[k].x); acc[k].y = fmaf(w0, f0.y, acc[k].y);
          den[k] += w0;
        }
      }
    }
    __syncthreads();   // before next chunk overwrites ws
  }

  // write out (B pre-holds the skip term)
#pragma unroll
  for (int k = 0; k < 8; k++) {
    int dl = gid * 8 + k;
    if (dl < ndst) {
      __half2* bp = (__half2*)(Bh + (size_t)(d0 + dl) * 64) + hl;
      float2 old = __half22float2(*bp);
      float inv = 1.f / (den[k] + 1e-16f);
      old.x += acc[k].x * inv;
      old.y += acc[k].y * inv;
      *bp = __float22half2_rn(old);
    }
  }
}

// ---------------- pooling ----------------
__global__ __launch_bounds__(256) void k_pool(
    const __half* __restrict__ H, const int* __restrict__ batch,
    float* __restrict__ pooled, int* __restrict__ cnt, int n) {
  int lane = threadIdx.x & 63;
  int w = threadIdx.x >> 6;
  int n0 = blockIdx.x * 64 + w * 16;
  float acc = 0.f;
  int cur = -1, nc = 0;
  for (int i = 0; i < 16; i++) {
    int node = n0 + i;
    if (node >= n) break;
    int g = batch[node];
    if (g != cur) {
      if (cur >= 0) {
        atomicAdd(&pooled[cur * 64 + lane], acc);
        if (lane == 0) atomicAdd(&cnt[cur], nc);
      }
      cur = g;
      acc = 0.f;
      nc = 0;
    }
    acc += __half2float(H[(size_t)node * 64 + lane]);
    nc++;
  }
  if (cur >= 0) {
    atomicAdd(&pooled[cur * 64 + lane], acc);
    if (lane == 0) atomicAdd(&cnt[cur], nc);
  }
}

__global__ void k_out(const float* __restrict__ pooled, const int* __restrict__ cnt,
                      const float* __restrict__ Wf, const float* __restrict__ bf,
                      float* __restrict__ out) {
  int g = blockIdx.x;
  int lane = threadIdx.x;
  int c = cnt[g];
  float cf = (float)(c > 1 ? c : 1);
  float mean = pooled[g * 64 + lane] / cf;
#pragma unroll
  for (int o = 0; o < OUTF; o++) {
    float p = wave_reduce_sum(mean * Wf[lane * OUTF + o]);
    if (lane == 0) out[g * OUTF + o] = p + bf[o];
  }
}

// ---------------- launch ----------------
extern "C" void kernel_launch(void* const* d_in, const int* in_sizes, int n_in,
                              void* d_out, int out_size, void* d_ws, size_t ws_size,
                              hipStream_t stream) {
  const float* x   = (const float*)d_in[0];
  const int* ei    = (const int*)d_in[1];
  const int* batch = (const int*)d_in[2];
  const float *Wq0 = (const float*)d_in[3],  *bq0 = (const float*)d_in[4];
  const float *Wk0 = (const float*)d_in[5],  *bk0 = (const float*)d_in[6];
  const float *Wv0 = (const float*)d_in[7],  *bv0 = (const float*)d_in[8];
  const float *Ws0 = (const float*)d_in[9],  *bs0 = (const float*)d_in[10];
  const float *Wqh = (const float*)d_in[11], *bqh = (const float*)d_in[12];
  const float *Wkh = (const float*)d_in[13], *bkh = (const float*)d_in[14];
  const float *Wvh = (const float*)d_in[15], *bvh = (const float*)d_in[16];
  const float *Wsh = (const float*)d_in[17], *bsh = (const float*)d_in[18];
  const float *Wf  = (const float*)d_in[19], *bf  = (const float*)d_in[20];

  __half* qh = (__half*)d_ws;
  __half* kh = qh + (size_t)NN * 64;
  __half* vh = kh + (size_t)NN * 64;
  __half* B0 = vh + (size_t)NN * 64;
  __half* B1 = B0 + (size_t)NN * 64;
  float* pooled = (float*)(B1 + (size_t)NN * 64);
  int* cnt     = (int*)(pooled + GG * 64);
  int* row_ptr = cnt + GG;
  int* col     = row_ptr + NN + 2;
  int* hblk    = col + EE;
  int* incl2   = hblk + LEN;
  int* bsum2   = incl2 + LEN;
  int* boff2   = bsum2 + 128;
  int* eoff    = boff2 + 128;
  int2* ebuf   = (int2*)((((uintptr_t)(eoff + LEN)) + 15) & ~(uintptr_t)15);
  __half* Pall = (__half*)(ebuf + EE);   // 16 slots x 4096 halves = 128KB

  hipMemsetAsync(pooled, 0, (GG * 64 + GG) * sizeof(float), stream);

  // weight pre-pack (once per call; all 16 matrices)
  k_wpack<<<16, 256, 0, stream>>>(Wq0, Wk0, Wv0, Ws0, Wqh, Wkh, Wvh, Wsh, Pall);

  // bucketed CSR build (once per call; reused by all 4 layers)
  k_bh<<<EB, 256, 0, stream>>>(ei, hblk);
  int nb2 = (LEN + 1023) / 1024;
  k_scan1<<<nb2, 256, 0, stream>>>(hblk, incl2, bsum2, LEN);
  k_scan2<<<1, 64, 0, stream>>>(bsum2, boff2, nb2);
  k_eoff<<<(LEN + 255) / 256, 256, 0, stream>>>(incl2, boff2, hblk, eoff, LEN);
  k_binwrite<<<EB, 256, 0, stream>>>(ei, eoff, ebuf);
  k_bcsr<<<NBUK, 256, 0, stream>>>(ebuf, eoff, row_ptr, col, NN);

  int gg = (NN + 63) / 64;
  int ga = (NN + FB_DST - 1) / FB_DST;  // 32 dsts per block, 128 threads

  // layer 0 (F_IN=16, fp32 input)
  k_gemm_mfma<FIN, float><<<gg, 256, 0, stream>>>(
      x, Pall, Pall + 4096, Pall + 2 * 4096, Pall + 3 * 4096,
      bq0, bk0, bv0, bs0, qh, kh, vh, B0, NN);
  k_fused<<<ga, 128, 0, stream>>>(qh, kh, vh, row_ptr, col, B0, NN);

  // hidden layers (H=64, fp16 h), ping-pong B0 <-> B1
  const __half* hin = B0;
  __half* hout = B1;
  for (int i = 0; i < NHID; i++) {
    const __half* Pb = Pall + (size_t)(4 + i * 4) * 4096;
    k_gemm_mfma<HH, __half><<<gg, 256, 0, stream>>>(
        hin, Pb, Pb + 4096, Pb + 2 * 4096, Pb + 3 * 4096,
        bqh + i * 64, bkh + i * 64, bvh + i * 64, bsh + i * 64,
        qh, kh, vh, hout, NN);
    k_fused<<<ga, 128, 0, stream>>>(qh, kh, vh, row_ptr, col, hout, NN);
    __half* t = (__half*)hin; hin = hout; hout = t;
  }

  k_pool<<<(NN + 63) / 64, 256, 0, stream>>>(hin, batch, pooled, cnt, NN);
  k_out<<<GG, 64, 0, stream>>>(pooled, cnt, Wf, bf, (float*)d_out);
}

// Round 9
// 468.562 us; speedup vs baseline: 1.5881x; 1.0313x over previous
//
#include <hip/hip_runtime.h>
#include <hip/hip_fp16.h>
#include <math.h>
#include <stdint.h>
#include <type_traits>

#define NN   100000
#define EE   1200000
#define GG   128
#define FIN  16
#define HH   64
#define OUTF 5
#define NHID 3

#define CE   4096                       // edges per block in bucket phases
#define EB   ((EE + CE - 1) / CE)       // 293 edge-blocks
#define NBUK ((NN + 511) >> 9)          // 196 buckets of 512 nodes
#define LEN  (NBUK * EB)                // hblk/eoff length

#define SRCMASK 0x03FFFFFFu             // low 26 bits of packed col entry
#define FB_DST 32                       // dsts per fused block

typedef _Float16 f16x8 __attribute__((ext_vector_type(8)));
typedef _Float16 f16x2 __attribute__((ext_vector_type(2)));
typedef float f32x4 __attribute__((ext_vector_type(4)));

#if defined(__has_builtin)
#if __has_builtin(__builtin_amdgcn_fdot2)
#define HAVE_FDOT2 1
#endif
#endif

static __device__ __forceinline__ float dot8_f16(f16x8 a, f16x8 b) {
#ifdef HAVE_FDOT2
  float ds = 0.f;
#pragma unroll
  for (int u = 0; u < 4; u++) {
    f16x2 x = {a[2 * u], a[2 * u + 1]};
    f16x2 y = {b[2 * u], b[2 * u + 1]};
    ds = __builtin_amdgcn_fdot2(x, y, ds, false);
  }
  return ds;
#else
  float ds = 0.f;
#pragma unroll
  for (int u = 0; u < 8; u++) ds += (float)a[u] * (float)b[u];
  return ds;
#endif
}

// ---------------- wave helpers ----------------
static __device__ __forceinline__ float wave_reduce_sum(float p) {
#pragma unroll
  for (int m = 32; m >= 1; m >>= 1) p += __shfl_xor(p, m, 64);
  return p;
}

// ---------------- bucketed CSR build ----------------
__global__ void k_bh(const int* __restrict__ ei, int* __restrict__ hblk) {
  __shared__ int h[NBUK];
  int tid = threadIdx.x, blk = blockIdx.x;
  for (int i = tid; i < NBUK; i += 256) h[i] = 0;
  __syncthreads();
  int base = blk * CE;
  for (int i = tid; i < CE; i += 256) {
    int e = base + i;
    if (e < EE) atomicAdd(&h[ei[EE + e] >> 9], 1);
  }
  __syncthreads();
  for (int i = tid; i < NBUK; i += 256) hblk[i * EB + blk] = h[i];
}

__global__ void k_scan1(const int* __restrict__ in, int* __restrict__ incl,
                        int* __restrict__ bsum, int n) {
  __shared__ int sd[256];
  int t = threadIdx.x, blk = blockIdx.x;
  int base = blk * 1024 + t * 4;
  int v[4];
#pragma unroll
  for (int i = 0; i < 4; i++) v[i] = (base + i < n) ? in[base + i] : 0;
  int s = v[0] + v[1] + v[2] + v[3];
  sd[t] = s;
  __syncthreads();
  for (int off = 1; off < 256; off <<= 1) {
    int x = 0;
    if (t >= off) x = sd[t - off];
    __syncthreads();
    if (t >= off) sd[t] += x;
    __syncthreads();
  }
  int run = sd[t] - s;
#pragma unroll
  for (int i = 0; i < 4; i++) {
    run += v[i];
    if (base + i < n) incl[base + i] = run;
  }
  if (t == 255) bsum[blk] = sd[255];
}

__global__ void k_scan2(const int* __restrict__ bsum, int* __restrict__ boff, int nb) {
  if (threadIdx.x == 0 && blockIdx.x == 0) {
    int run = 0;
    for (int i = 0; i < nb; i++) { boff[i] = run; run += bsum[i]; }
  }
}

__global__ void k_eoff(const int* __restrict__ incl, const int* __restrict__ boff,
                       const int* __restrict__ hblk, int* __restrict__ eoff, int n) {
  int t = blockIdx.x * blockDim.x + threadIdx.x;
  if (t < n) eoff[t] = incl[t] + boff[t / 1024] - hblk[t];
}

__global__ void k_binwrite(const int* __restrict__ ei, const int* __restrict__ eoff,
                           int2* __restrict__ ebuf) {
  __shared__ int cur[NBUK];
  int tid = threadIdx.x, blk = blockIdx.x;
  for (int i = tid; i < NBUK; i += 256) cur[i] = eoff[i * EB + blk];
  __syncthreads();
  int base = blk * CE;
  for (int i = tid; i < CE; i += 256) {
    int e = base + i;
    if (e < EE) {
      int d = ei[EE + e];
      int s = ei[e];
      int p = atomicAdd(&cur[d >> 9], 1);
      ebuf[p] = make_int2(s, d);
    }
  }
}

// merged bdeg2 + binscatter: histogram -> scan -> row_ptr -> cursors ->
// scatter col. col entry packs dst-mod-64 into bits 26..31 (unused by the
// R23 fused kernel, masked off harmlessly); src (<2^26) in low bits.
__global__ void k_bcsr(const int2* __restrict__ ebuf, const int* __restrict__ eoff,
                       int* __restrict__ row_ptr, int* __restrict__ col, int n) {
  __shared__ int dl[512];
  __shared__ int ps[256];
  int b = blockIdx.x, tid = threadIdx.x;
  int d0 = b << 9;
  dl[tid] = 0; dl[tid + 256] = 0;
  __syncthreads();
  int s0 = eoff[b * EB];
  int s1 = (b + 1 < NBUK) ? eoff[(b + 1) * EB] : EE;
  for (int e = s0 + tid; e < s1; e += 256) atomicAdd(&dl[ebuf[e].y - d0], 1);
  __syncthreads();
  int a0 = dl[2 * tid], a1 = dl[2 * tid + 1];
  ps[tid] = a0 + a1;
  __syncthreads();
  for (int off = 1; off < 256; off <<= 1) {
    int x = 0;
    if (tid >= off) x = ps[tid - off];
    __syncthreads();
    if (tid >= off) ps[tid] += x;
    __syncthreads();
  }
  int epair = ps[tid] - (a0 + a1);     // exclusive prefix of this pair
  int r0 = s0 + epair;
  int r1 = r0 + a0;
  int i0 = d0 + 2 * tid;
  if (i0 <= n) row_ptr[i0] = r0;       // covers row_ptr[n] = EE
  if (i0 + 1 <= n) row_ptr[i0 + 1] = r1;
  __syncthreads();
  dl[2 * tid] = r0;                    // reuse histogram LDS as cursors
  dl[2 * tid + 1] = r1;
  __syncthreads();
  for (int e = s0 + tid; e < s1; e += 256) {
    int2 sd = ebuf[e];
    int p = atomicAdd(&dl[sd.y - d0], 1);
    col[p] = (int)(((unsigned)sd.x) | (((unsigned)sd.y & 63u) << 26));
  }
}

// ---------------- projections via MFMA (R20-proven, best-measured) ----------
template <int F, typename TIN>
__global__ __launch_bounds__(256) void k_gemm_mfma(
    const TIN* __restrict__ X,
    const float* __restrict__ Wq, const float* __restrict__ bq,
    const float* __restrict__ Wk, const float* __restrict__ bk,
    const float* __restrict__ Wv, const float* __restrict__ bv,
    const float* __restrict__ Ws, const float* __restrict__ bs,
    __half* __restrict__ qh, __half* __restrict__ kh, __half* __restrict__ vh,
    __half* __restrict__ Bh, int n) {
  constexpr int KH = (F + 31) / 32;
  constexpr int S = KH * 32 + 8;
  __shared__ _Float16 xs[64 * S];
  int tid = threadIdx.x;
  int lane = tid & 63;
  int wv = tid >> 6;
  int quad = lane >> 4;
  int li = lane & 15;
  int node0 = blockIdx.x * 64;

  if constexpr (std::is_same<TIN, float>::value) {
    constexpr int F4 = F / 4;
    constexpr int CNT = 64 * F4 / 256;
#pragma unroll
    for (int i = 0; i < CNT; i++) {
      int idx = tid + i * 256;
      int nd = idx / F4;
      int kb = (idx % F4) * 4;
      float4 p;
      if (node0 + nd < n) p = *(const float4*)(X + (size_t)(node0 + nd) * F + kb);
      else p = make_float4(0.f, 0.f, 0.f, 0.f);
      _Float16* d = xs + nd * S + kb;
      d[0] = (_Float16)p.x; d[1] = (_Float16)p.y;
      d[2] = (_Float16)p.z; d[3] = (_Float16)p.w;
    }
    if (F == 16) {  // zero-pad k in [16,32)
      int nd = tid >> 2;
      int kb = 16 + (tid & 3) * 4;
      _Float16* d = xs + nd * S + kb;
      d[0] = 0; d[1] = 0; d[2] = 0; d[3] = 0;
    }
  } else {
    constexpr int F8 = F / 8;
    constexpr int CNT = 64 * F8 / 256;
#pragma unroll
    for (int i = 0; i < CNT; i++) {
      int idx = tid + i * 256;
      int nd = idx / F8;
      int kb = (idx % F8) * 8;
      f16x8 p = {};
      if (node0 + nd < n)
        p = *(const f16x8*)((const _Float16*)X + (size_t)(node0 + nd) * F + kb);
      *(f16x8*)(xs + nd * S + kb) = p;
    }
  }

  const float* W; const float* bias;
  if (wv == 0)      { W = Wq; bias = bq; }
  else if (wv == 1) { W = Wk; bias = bk; }
  else if (wv == 2) { W = Wv; bias = bv; }
  else              { W = Ws; bias = bs; }

  f16x8 bf[4][KH];
#pragma unroll
  for (int ns = 0; ns < 4; ns++)
#pragma unroll
    for (int kh2 = 0; kh2 < KH; kh2++)
#pragma unroll
      for (int j = 0; j < 8; j++) {
        int kidx = kh2 * 32 + quad * 8 + j;
        bf[ns][kh2][j] = (kidx < F)
            ? (_Float16)W[(size_t)kidx * 64 + ns * 16 + li] : (_Float16)0.f;
      }
  float blv[4];
#pragma unroll
  for (int ns = 0; ns < 4; ns++) blv[ns] = bias[ns * 16 + li];

  __syncthreads();

  f16x8 af[4][KH];
#pragma unroll
  for (int ms = 0; ms < 4; ms++)
#pragma unroll
    for (int kh2 = 0; kh2 < KH; kh2++)
      af[ms][kh2] = *(const f16x8*)(xs + (ms * 16 + li) * S + kh2 * 32 + quad * 8);

  f32x4 acc[4][4];
#pragma unroll
  for (int ms = 0; ms < 4; ms++)
#pragma unroll
    for (int ns = 0; ns < 4; ns++) {
      float b = blv[ns];
      acc[ms][ns] = (f32x4){b, b, b, b};
    }
#pragma unroll
  for (int kh2 = 0; kh2 < KH; kh2++)
#pragma unroll
    for (int ms = 0; ms < 4; ms++)
#pragma unroll
      for (int ns = 0; ns < 4; ns++)
        acc[ms][ns] = __builtin_amdgcn_mfma_f32_16x16x32_f16(
            af[ms][kh2], bf[ns][kh2], acc[ms][ns], 0, 0, 0);

  __half* outh = (wv == 0) ? qh : (wv == 1) ? kh : (wv == 2) ? vh : Bh;
#pragma unroll
  for (int ms = 0; ms < 4; ms++)
#pragma unroll
    for (int ns = 0; ns < 4; ns++) {
      int colc = ns * 16 + li;
#pragma unroll
      for (int r = 0; r < 4; r++) {
        int node = node0 + ms * 16 + quad * 4 + r;
        if (node < n)
          outh[(size_t)node * 64 + colc] = __float2half(acc[ms][ns][r]);
      }
    }
}

// ---------------- fused attention, merged single-pass (R23) ----------------
// Block = 32 dsts, 128 threads, 16 groups x 8 lanes; each group OWNS 2
// consecutive dsts (~24 edges total serial vs R20 phase B's 96). Per edge:
// 8 lanes gather k[src] AND v[src] (one 128B transaction each — R21 lesson:
// keep cooperative row gathers), dot vs q held in REGISTERS (2x f16x8),
// 3-shfl 8-lane reduce, exp, fma pe*v into register acc[2][8]. Kills the
// ws.y LDS round-trip, one barrier/chunk, and the 32-lane redundant den.
// exp w/o max-subtract is associative across chunks.
__global__ __launch_bounds__(128) void k_fused(
    const __half* __restrict__ qh, const __half* __restrict__ kh,
    const __half* __restrict__ vh, const int* __restrict__ row_ptr,
    const int* __restrict__ col, __half* __restrict__ Bh, int n) {
  __shared__ int ws[1024];
  __shared__ int rpl[FB_DST + 1];
  int tid = threadIdx.x;
  int d0 = blockIdx.x * FB_DST;
  int ndst = n - d0; if (ndst > FB_DST) ndst = FB_DST;

  if (tid < FB_DST + 1) {
    int dd = d0 + tid; if (dd > n) dd = n;
    rpl[tid] = row_ptr[dd];
  }
  __syncthreads();
  int e0 = rpl[0], e1 = rpl[ndst];

  int g = tid >> 3, aj = tid & 7;     // 16 groups x 8 lanes

  f16x8 qv[2] = {};
  float acc[2][8];
  float den[2];
#pragma unroll
  for (int t = 0; t < 2; t++) {
    den[t] = 0.f;
#pragma unroll
    for (int u = 0; u < 8; u++) acc[t][u] = 0.f;
    int dl = 2 * g + t;
    if (dl < ndst)
      qv[t] = *(const f16x8*)((const _Float16*)qh + (size_t)(d0 + dl) * 64 + aj * 8);
  }

  for (int c0 = e0; c0 < e1; c0 += 1024) {
    int cn = e1 - c0; if (cn > 1024) cn = 1024;
#pragma unroll
    for (int s = 0; s < 8; s++) {      // stage col chunk, coalesced
      int i = tid + s * 128;
      if (i < cn) ws[i] = col[c0 + i];
    }
    __syncthreads();

#pragma unroll
    for (int t = 0; t < 2; t++) {
      int dl = 2 * g + t;
      if (dl < ndst) {
        int lo = rpl[dl];     if (lo < c0) lo = c0;
        int hi = rpl[dl + 1]; int ce = c0 + cn; if (hi > ce) hi = ce;
        int i = lo - c0, iend = hi - c0;
        for (; i + 2 <= iend; i += 2) {
          int s0 = ws[i] & (int)SRCMASK;
          int s1 = ws[i + 1] & (int)SRCMASK;
          f16x8 k0 = *(const f16x8*)((const _Float16*)kh + (size_t)s0 * 64 + aj * 8);
          f16x8 v0 = *(const f16x8*)((const _Float16*)vh + (size_t)s0 * 64 + aj * 8);
          f16x8 k1 = *(const f16x8*)((const _Float16*)kh + (size_t)s1 * 64 + aj * 8);
          f16x8 v1 = *(const f16x8*)((const _Float16*)vh + (size_t)s1 * 64 + aj * 8);
          float da = dot8_f16(qv[t], k0);
          float db = dot8_f16(qv[t], k1);
          da += __shfl_xor(da, 1, 64); db += __shfl_xor(db, 1, 64);
          da += __shfl_xor(da, 2, 64); db += __shfl_xor(db, 2, 64);
          da += __shfl_xor(da, 4, 64); db += __shfl_xor(db, 4, 64);
          float pa = __expf(fminf(da * 0.125f, 60.f));   // 1/sqrt(64)
          float pb = __expf(fminf(db * 0.125f, 60.f));
          den[t] += pa + pb;
#pragma unroll
          for (int u = 0; u < 8; u++) {
            acc[t][u] = fmaf(pa, (float)v0[u], acc[t][u]);
            acc[t][u] = fmaf(pb, (float)v1[u], acc[t][u]);
          }
        }
        if (i < iend) {
          int s0 = ws[i] & (int)SRCMASK;
          f16x8 k0 = *(const f16x8*)((const _Float16*)kh + (size_t)s0 * 64 + aj * 8);
          f16x8 v0 = *(const f16x8*)((const _Float16*)vh + (size_t)s0 * 64 + aj * 8);
          float da = dot8_f16(qv[t], k0);
          da += __shfl_xor(da, 1, 64);
          da += __shfl_xor(da, 2, 64);
          da += __shfl_xor(da, 4, 64);
          float pa = __expf(fminf(da * 0.125f, 60.f));
          den[t] += pa;
#pragma unroll
          for (int u = 0; u < 8; u++)
            acc[t][u] = fmaf(pa, (float)v0[u], acc[t][u]);
        }
      }
    }
    __syncthreads();   // before next chunk overwrites ws
  }

  // write out (B pre-holds the skip term); 8 lanes cover one dst row
#pragma unroll
  for (int t = 0; t < 2; t++) {
    int dl = 2 * g + t;
    if (dl < ndst) {
      _Float16* bp = (_Float16*)Bh + (size_t)(d0 + dl) * 64 + aj * 8;
      f16x8 old = *(const f16x8*)bp;
      float inv = 1.f / (den[t] + 1e-16f);
      f16x8 o;
#pragma unroll
      for (int u = 0; u < 8; u++)
        o[u] = (_Float16)((float)old[u] + acc[t][u] * inv);
      *(f16x8*)bp = o;
    }
  }
}

// ---------------- pooling ----------------
__global__ __launch_bounds__(256) void k_pool(
    const __half* __restrict__ H, const int* __restrict__ batch,
    float* __restrict__ pooled, int* __restrict__ cnt, int n) {
  int lane = threadIdx.x & 63;
  int w = threadIdx.x >> 6;
  int n0 = blockIdx.x * 64 + w * 16;
  float acc = 0.f;
  int cur = -1, nc = 0;
  for (int i = 0; i < 16; i++) {
    int node = n0 + i;
    if (node >= n) break;
    int g = batch[node];
    if (g != cur) {
      if (cur >= 0) {
        atomicAdd(&pooled[cur * 64 + lane], acc);
        if (lane == 0) atomicAdd(&cnt[cur], nc);
      }
      cur = g;
      acc = 0.f;
      nc = 0;
    }
    acc += __half2float(H[(size_t)node * 64 + lane]);
    nc++;
  }
  if (cur >= 0) {
    atomicAdd(&pooled[cur * 64 + lane], acc);
    if (lane == 0) atomicAdd(&cnt[cur], nc);
  }
}

__global__ void k_out(const float* __restrict__ pooled, const int* __restrict__ cnt,
                      const float* __restrict__ Wf, const float* __restrict__ bf,
                      float* __restrict__ out) {
  int g = blockIdx.x;
  int lane = threadIdx.x;
  int c = cnt[g];
  float cf = (float)(c > 1 ? c : 1);
  float mean = pooled[g * 64 + lane] / cf;
#pragma unroll
  for (int o = 0; o < OUTF; o++) {
    float p = wave_reduce_sum(mean * Wf[lane * OUTF + o]);
    if (lane == 0) out[g * OUTF + o] = p + bf[o];
  }
}

// ---------------- launch ----------------
extern "C" void kernel_launch(void* const* d_in, const int* in_sizes, int n_in,
                              void* d_out, int out_size, void* d_ws, size_t ws_size,
                              hipStream_t stream) {
  const float* x   = (const float*)d_in[0];
  const int* ei    = (const int*)d_in[1];
  const int* batch = (const int*)d_in[2];
  const float *Wq0 = (const float*)d_in[3],  *bq0 = (const float*)d_in[4];
  const float *Wk0 = (const float*)d_in[5],  *bk0 = (const float*)d_in[6];
  const float *Wv0 = (const float*)d_in[7],  *bv0 = (const float*)d_in[8];
  const float *Ws0 = (const float*)d_in[9],  *bs0 = (const float*)d_in[10];
  const float *Wqh = (const float*)d_in[11], *bqh = (const float*)d_in[12];
  const float *Wkh = (const float*)d_in[13], *bkh = (const float*)d_in[14];
  const float *Wvh = (const float*)d_in[15], *bvh = (const float*)d_in[16];
  const float *Wsh = (const float*)d_in[17], *bsh = (const float*)d_in[18];
  const float *Wf  = (const float*)d_in[19], *bf  = (const float*)d_in[20];

  __half* qh = (__half*)d_ws;
  __half* kh = qh + (size_t)NN * 64;
  __half* vh = kh + (size_t)NN * 64;
  __half* B0 = vh + (size_t)NN * 64;
  __half* B1 = B0 + (size_t)NN * 64;
  float* pooled = (float*)(B1 + (size_t)NN * 64);
  int* cnt     = (int*)(pooled + GG * 64);
  int* row_ptr = cnt + GG;
  int* col     = row_ptr + NN + 2;
  int* hblk    = col + EE;
  int* incl2   = hblk + LEN;
  int* bsum2   = incl2 + LEN;
  int* boff2   = bsum2 + 128;
  int* eoff    = boff2 + 128;
  int2* ebuf   = (int2*)((((uintptr_t)(eoff + LEN)) + 15) & ~(uintptr_t)15);

  hipMemsetAsync(pooled, 0, (GG * 64 + GG) * sizeof(float), stream);

  // bucketed CSR build (once per call; reused by all 4 layers)
  k_bh<<<EB, 256, 0, stream>>>(ei, hblk);
  int nb2 = (LEN + 1023) / 1024;
  k_scan1<<<nb2, 256, 0, stream>>>(hblk, incl2, bsum2, LEN);
  k_scan2<<<1, 64, 0, stream>>>(bsum2, boff2, nb2);
  k_eoff<<<(LEN + 255) / 256, 256, 0, stream>>>(incl2, boff2, hblk, eoff, LEN);
  k_binwrite<<<EB, 256, 0, stream>>>(ei, eoff, ebuf);
  k_bcsr<<<NBUK, 256, 0, stream>>>(ebuf, eoff, row_ptr, col, NN);

  int gg = (NN + 63) / 64;
  int ga = (NN + FB_DST - 1) / FB_DST;  // 32 dsts per block, 128 threads

  // layer 0 (F_IN=16, fp32 input)
  k_gemm_mfma<FIN, float><<<gg, 256, 0, stream>>>(
      x, Wq0, bq0, Wk0, bk0, Wv0, bv0, Ws0, bs0, qh, kh, vh, B0, NN);
  k_fused<<<ga, 128, 0, stream>>>(qh, kh, vh, row_ptr, col, B0, NN);

  // hidden layers (H=64, fp16 h), ping-pong B0 <-> B1
  const __half* hin = B0;
  __half* hout = B1;
  for (int i = 0; i < NHID; i++) {
    k_gemm_mfma<HH, __half><<<gg, 256, 0, stream>>>(
        hin, Wqh + i * 4096, bqh + i * 64,
        Wkh + i * 4096, bkh + i * 64,
        Wvh + i * 4096, bvh + i * 64,
        Wsh + i * 4096, bsh + i * 64,
        qh, kh, vh, hout, NN);
    k_fused<<<ga, 128, 0, stream>>>(qh, kh, vh, row_ptr, col, hout, NN);
    __half* t = (__half*)hin; hin = hout; hout = t;
  }

  k_pool<<<(NN + 63) / 64, 256, 0, stream>>>(hin, batch, pooled, cnt, NN);
  k_out<<<GG, 64, 0, stream>>>(pooled, cnt, Wf, bf, (float*)d_out);
}

// Round 10
// 430.713 us; speedup vs baseline: 1.7277x; 1.0879x over previous
//
#include <hip/hip_runtime.h>
#include <hip/hip_fp16.h>
#include <math.h>
#include <stdint.h>
#include <type_traits>

#define NN   100000
#define EE   1200000
#define GG   128
#define FIN  16
#define HH   64
#define OUTF 5
#define NHID 3

#define CE   4096                       // edges per block in bucket phases
#define EB   ((EE + CE - 1) / CE)       // 293 edge-blocks
#define NBUK ((NN + 511) >> 9)          // 196 buckets of 512 nodes
#define LEN  (NBUK * EB)                // hblk/eoff length

#define SRCMASK 0x03FFFFFFu             // low 26 bits of packed col entry
#define FB_DST 32                       // dsts per fused block

typedef _Float16 f16x8 __attribute__((ext_vector_type(8)));
typedef _Float16 f16x2 __attribute__((ext_vector_type(2)));
typedef float f32x4 __attribute__((ext_vector_type(4)));

#if defined(__has_builtin)
#if __has_builtin(__builtin_amdgcn_fdot2)
#define HAVE_FDOT2 1
#endif
#endif

static __device__ __forceinline__ float dot8_f16(f16x8 a, f16x8 b) {
#ifdef HAVE_FDOT2
  float ds = 0.f;
#pragma unroll
  for (int u = 0; u < 4; u++) {
    f16x2 x = {a[2 * u], a[2 * u + 1]};
    f16x2 y = {b[2 * u], b[2 * u + 1]};
    ds = __builtin_amdgcn_fdot2(x, y, ds, false);
  }
  return ds;
#else
  float ds = 0.f;
#pragma unroll
  for (int u = 0; u < 8; u++) ds += (float)a[u] * (float)b[u];
  return ds;
#endif
}

// ---------------- wave helpers ----------------
static __device__ __forceinline__ float wave_reduce_sum(float p) {
#pragma unroll
  for (int m = 32; m >= 1; m >>= 1) p += __shfl_xor(p, m, 64);
  return p;
}

// ---------------- bucketed CSR build ----------------
__global__ void k_bh(const int* __restrict__ ei, int* __restrict__ hblk) {
  __shared__ int h[NBUK];
  int tid = threadIdx.x, blk = blockIdx.x;
  for (int i = tid; i < NBUK; i += 256) h[i] = 0;
  __syncthreads();
  int base = blk * CE;
  for (int i = tid; i < CE; i += 256) {
    int e = base + i;
    if (e < EE) atomicAdd(&h[ei[EE + e] >> 9], 1);
  }
  __syncthreads();
  for (int i = tid; i < NBUK; i += 256) hblk[i * EB + blk] = h[i];
}

__global__ void k_scan1(const int* __restrict__ in, int* __restrict__ incl,
                        int* __restrict__ bsum, int n) {
  __shared__ int sd[256];
  int t = threadIdx.x, blk = blockIdx.x;
  int base = blk * 1024 + t * 4;
  int v[4];
#pragma unroll
  for (int i = 0; i < 4; i++) v[i] = (base + i < n) ? in[base + i] : 0;
  int s = v[0] + v[1] + v[2] + v[3];
  sd[t] = s;
  __syncthreads();
  for (int off = 1; off < 256; off <<= 1) {
    int x = 0;
    if (t >= off) x = sd[t - off];
    __syncthreads();
    if (t >= off) sd[t] += x;
    __syncthreads();
  }
  int run = sd[t] - s;
#pragma unroll
  for (int i = 0; i < 4; i++) {
    run += v[i];
    if (base + i < n) incl[base + i] = run;
  }
  if (t == 255) bsum[blk] = sd[255];
}

__global__ void k_scan2(const int* __restrict__ bsum, int* __restrict__ boff, int nb) {
  if (threadIdx.x == 0 && blockIdx.x == 0) {
    int run = 0;
    for (int i = 0; i < nb; i++) { boff[i] = run; run += bsum[i]; }
  }
}

__global__ void k_eoff(const int* __restrict__ incl, const int* __restrict__ boff,
                       const int* __restrict__ hblk, int* __restrict__ eoff, int n) {
  int t = blockIdx.x * blockDim.x + threadIdx.x;
  if (t < n) eoff[t] = incl[t] + boff[t / 1024] - hblk[t];
}

__global__ void k_binwrite(const int* __restrict__ ei, const int* __restrict__ eoff,
                           int2* __restrict__ ebuf) {
  __shared__ int cur[NBUK];
  int tid = threadIdx.x, blk = blockIdx.x;
  for (int i = tid; i < NBUK; i += 256) cur[i] = eoff[i * EB + blk];
  __syncthreads();
  int base = blk * CE;
  for (int i = tid; i < CE; i += 256) {
    int e = base + i;
    if (e < EE) {
      int d = ei[EE + e];
      int s = ei[e];
      int p = atomicAdd(&cur[d >> 9], 1);
      ebuf[p] = make_int2(s, d);
    }
  }
}

// merged bdeg2 + binscatter: histogram -> scan -> row_ptr -> cursors ->
// scatter col. col entry packs dst-mod-64 into bits 26..31 (unused by the
// fused kernel, masked off harmlessly); src (<2^26) in low bits.
__global__ void k_bcsr(const int2* __restrict__ ebuf, const int* __restrict__ eoff,
                       int* __restrict__ row_ptr, int* __restrict__ col, int n) {
  __shared__ int dl[512];
  __shared__ int ps[256];
  int b = blockIdx.x, tid = threadIdx.x;
  int d0 = b << 9;
  dl[tid] = 0; dl[tid + 256] = 0;
  __syncthreads();
  int s0 = eoff[b * EB];
  int s1 = (b + 1 < NBUK) ? eoff[(b + 1) * EB] : EE;
  for (int e = s0 + tid; e < s1; e += 256) atomicAdd(&dl[ebuf[e].y - d0], 1);
  __syncthreads();
  int a0 = dl[2 * tid], a1 = dl[2 * tid + 1];
  ps[tid] = a0 + a1;
  __syncthreads();
  for (int off = 1; off < 256; off <<= 1) {
    int x = 0;
    if (tid >= off) x = ps[tid - off];
    __syncthreads();
    if (tid >= off) ps[tid] += x;
    __syncthreads();
  }
  int epair = ps[tid] - (a0 + a1);     // exclusive prefix of this pair
  int r0 = s0 + epair;
  int r1 = r0 + a0;
  int i0 = d0 + 2 * tid;
  if (i0 <= n) row_ptr[i0] = r0;       // covers row_ptr[n] = EE
  if (i0 + 1 <= n) row_ptr[i0 + 1] = r1;
  __syncthreads();
  dl[2 * tid] = r0;                    // reuse histogram LDS as cursors
  dl[2 * tid + 1] = r1;
  __syncthreads();
  for (int e = s0 + tid; e < s1; e += 256) {
    int2 sd = ebuf[e];
    int p = atomicAdd(&dl[sd.y - d0], 1);
    col[p] = (int)(((unsigned)sd.x) | (((unsigned)sd.y & 63u) << 26));
  }
}

// ---------------- projections via MFMA (R20-proven, best-measured) ----------
template <int F, typename TIN>
__global__ __launch_bounds__(256) void k_gemm_mfma(
    const TIN* __restrict__ X,
    const float* __restrict__ Wq, const float* __restrict__ bq,
    const float* __restrict__ Wk, const float* __restrict__ bk,
    const float* __restrict__ Wv, const float* __restrict__ bv,
    const float* __restrict__ Ws, const float* __restrict__ bs,
    __half* __restrict__ qh, __half* __restrict__ kh, __half* __restrict__ vh,
    __half* __restrict__ Bh, int n) {
  constexpr int KH = (F + 31) / 32;
  constexpr int S = KH * 32 + 8;
  __shared__ _Float16 xs[64 * S];
  int tid = threadIdx.x;
  int lane = tid & 63;
  int wv = tid >> 6;
  int quad = lane >> 4;
  int li = lane & 15;
  int node0 = blockIdx.x * 64;

  if constexpr (std::is_same<TIN, float>::value) {
    constexpr int F4 = F / 4;
    constexpr int CNT = 64 * F4 / 256;
#pragma unroll
    for (int i = 0; i < CNT; i++) {
      int idx = tid + i * 256;
      int nd = idx / F4;
      int kb = (idx % F4) * 4;
      float4 p;
      if (node0 + nd < n) p = *(const float4*)(X + (size_t)(node0 + nd) * F + kb);
      else p = make_float4(0.f, 0.f, 0.f, 0.f);
      _Float16* d = xs + nd * S + kb;
      d[0] = (_Float16)p.x; d[1] = (_Float16)p.y;
      d[2] = (_Float16)p.z; d[3] = (_Float16)p.w;
    }
    if (F == 16) {  // zero-pad k in [16,32)
      int nd = tid >> 2;
      int kb = 16 + (tid & 3) * 4;
      _Float16* d = xs + nd * S + kb;
      d[0] = 0; d[1] = 0; d[2] = 0; d[3] = 0;
    }
  } else {
    constexpr int F8 = F / 8;
    constexpr int CNT = 64 * F8 / 256;
#pragma unroll
    for (int i = 0; i < CNT; i++) {
      int idx = tid + i * 256;
      int nd = idx / F8;
      int kb = (idx % F8) * 8;
      f16x8 p = {};
      if (node0 + nd < n)
        p = *(const f16x8*)((const _Float16*)X + (size_t)(node0 + nd) * F + kb);
      *(f16x8*)(xs + nd * S + kb) = p;
    }
  }

  const float* W; const float* bias;
  if (wv == 0)      { W = Wq; bias = bq; }
  else if (wv == 1) { W = Wk; bias = bk; }
  else if (wv == 2) { W = Wv; bias = bv; }
  else              { W = Ws; bias = bs; }

  f16x8 bf[4][KH];
#pragma unroll
  for (int ns = 0; ns < 4; ns++)
#pragma unroll
    for (int kh2 = 0; kh2 < KH; kh2++)
#pragma unroll
      for (int j = 0; j < 8; j++) {
        int kidx = kh2 * 32 + quad * 8 + j;
        bf[ns][kh2][j] = (kidx < F)
            ? (_Float16)W[(size_t)kidx * 64 + ns * 16 + li] : (_Float16)0.f;
      }
  float blv[4];
#pragma unroll
  for (int ns = 0; ns < 4; ns++) blv[ns] = bias[ns * 16 + li];

  __syncthreads();

  f16x8 af[4][KH];
#pragma unroll
  for (int ms = 0; ms < 4; ms++)
#pragma unroll
    for (int kh2 = 0; kh2 < KH; kh2++)
      af[ms][kh2] = *(const f16x8*)(xs + (ms * 16 + li) * S + kh2 * 32 + quad * 8);

  f32x4 acc[4][4];
#pragma unroll
  for (int ms = 0; ms < 4; ms++)
#pragma unroll
    for (int ns = 0; ns < 4; ns++) {
      float b = blv[ns];
      acc[ms][ns] = (f32x4){b, b, b, b};
    }
#pragma unroll
  for (int kh2 = 0; kh2 < KH; kh2++)
#pragma unroll
    for (int ms = 0; ms < 4; ms++)
#pragma unroll
      for (int ns = 0; ns < 4; ns++)
        acc[ms][ns] = __builtin_amdgcn_mfma_f32_16x16x32_f16(
            af[ms][kh2], bf[ns][kh2], acc[ms][ns], 0, 0, 0);

  __half* outh = (wv == 0) ? qh : (wv == 1) ? kh : (wv == 2) ? vh : Bh;
#pragma unroll
  for (int ms = 0; ms < 4; ms++)
#pragma unroll
    for (int ns = 0; ns < 4; ns++) {
      int colc = ns * 16 + li;
#pragma unroll
      for (int r = 0; r < 4; r++) {
        int node = node0 + ms * 16 + quad * 4 + r;
        if (node < n)
          outh[(size_t)node * 64 + colc] = __float2half(acc[ms][ns][r]);
      }
    }
}

// ---------------- fused attention, phase-split + register acc (R24) ---------
// R23 skeleton (2 dsts per 8-lane group, q + accumulators in registers,
// short ~24-edge chains) + R20's gather phase separation restored via LDS
// pw[]: K-pass does ONLY k-gathers (dot, shfl, exp -> den, pw[i]); block
// barrier; V-pass does ONLY v-gathers (pw[i] broadcast read, fma). The
// barrier phases the block's gather streams so L2 sees one 12.8MB array
// at a time (R23's interleaved k/v streams cost +19MB FETCH, measured).
// Each group reads only its own pw writes -> barrier is locality-only.
__global__ __launch_bounds__(128) void k_fused(
    const __half* __restrict__ qh, const __half* __restrict__ kh,
    const __half* __restrict__ vh, const int* __restrict__ row_ptr,
    const int* __restrict__ col, __half* __restrict__ Bh, int n) {
  __shared__ int ws[1024];
  __shared__ float pw[1024];
  __shared__ int rpl[FB_DST + 1];
  int tid = threadIdx.x;
  int d0 = blockIdx.x * FB_DST;
  int ndst = n - d0; if (ndst > FB_DST) ndst = FB_DST;

  if (tid < FB_DST + 1) {
    int dd = d0 + tid; if (dd > n) dd = n;
    rpl[tid] = row_ptr[dd];
  }
  __syncthreads();
  int e0 = rpl[0], e1 = rpl[ndst];

  int g = tid >> 3, aj = tid & 7;     // 16 groups x 8 lanes

  f16x8 qv[2] = {};
  float acc[2][8];
  float den[2];
#pragma unroll
  for (int t = 0; t < 2; t++) {
    den[t] = 0.f;
#pragma unroll
    for (int u = 0; u < 8; u++) acc[t][u] = 0.f;
    int dl = 2 * g + t;
    if (dl < ndst)
      qv[t] = *(const f16x8*)((const _Float16*)qh + (size_t)(d0 + dl) * 64 + aj * 8);
  }

  for (int c0 = e0; c0 < e1; c0 += 1024) {
    int cn = e1 - c0; if (cn > 1024) cn = 1024;
#pragma unroll
    for (int s = 0; s < 8; s++) {      // stage col chunk, coalesced
      int i = tid + s * 128;
      if (i < cn) ws[i] = col[c0 + i];
    }
    __syncthreads();

    // ---- K-pass: k-gathers only -> pe, den, pw ----
#pragma unroll
    for (int t = 0; t < 2; t++) {
      int dl = 2 * g + t;
      if (dl < ndst) {
        int lo = rpl[dl];     if (lo < c0) lo = c0;
        int hi = rpl[dl + 1]; int ce = c0 + cn; if (hi > ce) hi = ce;
        int i = lo - c0, iend = hi - c0;
        for (; i + 2 <= iend; i += 2) {
          int s0 = ws[i] & (int)SRCMASK;
          int s1 = ws[i + 1] & (int)SRCMASK;
          f16x8 k0 = *(const f16x8*)((const _Float16*)kh + (size_t)s0 * 64 + aj * 8);
          f16x8 k1 = *(const f16x8*)((const _Float16*)kh + (size_t)s1 * 64 + aj * 8);
          float da = dot8_f16(qv[t], k0);
          float db = dot8_f16(qv[t], k1);
          da += __shfl_xor(da, 1, 64); db += __shfl_xor(db, 1, 64);
          da += __shfl_xor(da, 2, 64); db += __shfl_xor(db, 2, 64);
          da += __shfl_xor(da, 4, 64); db += __shfl_xor(db, 4, 64);
          float pa = __expf(fminf(da * 0.125f, 60.f));   // 1/sqrt(64)
          float pb = __expf(fminf(db * 0.125f, 60.f));
          den[t] += pa + pb;
          if (aj == 0) { pw[i] = pa; pw[i + 1] = pb; }
        }
        if (i < iend) {
          int s0 = ws[i] & (int)SRCMASK;
          f16x8 k0 = *(const f16x8*)((const _Float16*)kh + (size_t)s0 * 64 + aj * 8);
          float da = dot8_f16(qv[t], k0);
          da += __shfl_xor(da, 1, 64);
          da += __shfl_xor(da, 2, 64);
          da += __shfl_xor(da, 4, 64);
          float pa = __expf(fminf(da * 0.125f, 60.f));
          den[t] += pa;
          if (aj == 0) pw[i] = pa;
        }
      }
    }
    __syncthreads();   // phase the gather streams (locality, not correctness)

    // ---- V-pass: v-gathers only; pw broadcast reads; fma into registers ----
#pragma unroll
    for (int t = 0; t < 2; t++) {
      int dl = 2 * g + t;
      if (dl < ndst) {
        int lo = rpl[dl];     if (lo < c0) lo = c0;
        int hi = rpl[dl + 1]; int ce = c0 + cn; if (hi > ce) hi = ce;
        int i = lo - c0, iend = hi - c0;
        for (; i + 2 <= iend; i += 2) {
          int s0 = ws[i] & (int)SRCMASK;
          int s1 = ws[i + 1] & (int)SRCMASK;
          float pa = pw[i], pb = pw[i + 1];
          f16x8 v0 = *(const f16x8*)((const _Float16*)vh + (size_t)s0 * 64 + aj * 8);
          f16x8 v1 = *(const f16x8*)((const _Float16*)vh + (size_t)s1 * 64 + aj * 8);
#pragma unroll
          for (int u = 0; u < 8; u++) {
            acc[t][u] = fmaf(pa, (float)v0[u], acc[t][u]);
            acc[t][u] = fmaf(pb, (float)v1[u], acc[t][u]);
          }
        }
        if (i < iend) {
          int s0 = ws[i] & (int)SRCMASK;
          float pa = pw[i];
          f16x8 v0 = *(const f16x8*)((const _Float16*)vh + (size_t)s0 * 64 + aj * 8);
#pragma unroll
          for (int u = 0; u < 8; u++)
            acc[t][u] = fmaf(pa, (float)v0[u], acc[t][u]);
        }
      }
    }
    __syncthreads();   // before next chunk overwrites ws/pw
  }

  // write out (B pre-holds the skip term); 8 lanes cover one dst row
#pragma unroll
  for (int t = 0; t < 2; t++) {
    int dl = 2 * g + t;
    if (dl < ndst) {
      _Float16* bp = (_Float16*)Bh + (size_t)(d0 + dl) * 64 + aj * 8;
      f16x8 old = *(const f16x8*)bp;
      float inv = 1.f / (den[t] + 1e-16f);
      f16x8 o;
#pragma unroll
      for (int u = 0; u < 8; u++)
        o[u] = (_Float16)((float)old[u] + acc[t][u] * inv);
      *(f16x8*)bp = o;
    }
  }
}

// ---------------- pooling ----------------
__global__ __launch_bounds__(256) void k_pool(
    const __half* __restrict__ H, const int* __restrict__ batch,
    float* __restrict__ pooled, int* __restrict__ cnt, int n) {
  int lane = threadIdx.x & 63;
  int w = threadIdx.x >> 6;
  int n0 = blockIdx.x * 64 + w * 16;
  float acc = 0.f;
  int cur = -1, nc = 0;
  for (int i = 0; i < 16; i++) {
    int node = n0 + i;
    if (node >= n) break;
    int g = batch[node];
    if (g != cur) {
      if (cur >= 0) {
        atomicAdd(&pooled[cur * 64 + lane], acc);
        if (lane == 0) atomicAdd(&cnt[cur], nc);
      }
      cur = g;
      acc = 0.f;
      nc = 0;
    }
    acc += __half2float(H[(size_t)node * 64 + lane]);
    nc++;
  }
  if (cur >= 0) {
    atomicAdd(&pooled[cur * 64 + lane], acc);
    if (lane == 0) atomicAdd(&cnt[cur], nc);
  }
}

__global__ void k_out(const float* __restrict__ pooled, const int* __restrict__ cnt,
                      const float* __restrict__ Wf, const float* __restrict__ bf,
                      float* __restrict__ out) {
  int g = blockIdx.x;
  int lane = threadIdx.x;
  int c = cnt[g];
  float cf = (float)(c > 1 ? c : 1);
  float mean = pooled[g * 64 + lane] / cf;
#pragma unroll
  for (int o = 0; o < OUTF; o++) {
    float p = wave_reduce_sum(mean * Wf[lane * OUTF + o]);
    if (lane == 0) out[g * OUTF + o] = p + bf[o];
  }
}

// ---------------- launch ----------------
extern "C" void kernel_launch(void* const* d_in, const int* in_sizes, int n_in,
                              void* d_out, int out_size, void* d_ws, size_t ws_size,
                              hipStream_t stream) {
  const float* x   = (const float*)d_in[0];
  const int* ei    = (const int*)d_in[1];
  const int* batch = (const int*)d_in[2];
  const float *Wq0 = (const float*)d_in[3],  *bq0 = (const float*)d_in[4];
  const float *Wk0 = (const float*)d_in[5],  *bk0 = (const float*)d_in[6];
  const float *Wv0 = (const float*)d_in[7],  *bv0 = (const float*)d_in[8];
  const float *Ws0 = (const float*)d_in[9],  *bs0 = (const float*)d_in[10];
  const float *Wqh = (const float*)d_in[11], *bqh = (const float*)d_in[12];
  const float *Wkh = (const float*)d_in[13], *bkh = (const float*)d_in[14];
  const float *Wvh = (const float*)d_in[15], *bvh = (const float*)d_in[16];
  const float *Wsh = (const float*)d_in[17], *bsh = (const float*)d_in[18];
  const float *Wf  = (const float*)d_in[19], *bf  = (const float*)d_in[20];

  __half* qh = (__half*)d_ws;
  __half* kh = qh + (size_t)NN * 64;
  __half* vh = kh + (size_t)NN * 64;
  __half* B0 = vh + (size_t)NN * 64;
  __half* B1 = B0 + (size_t)NN * 64;
  float* pooled = (float*)(B1 + (size_t)NN * 64);
  int* cnt     = (int*)(pooled + GG * 64);
  int* row_ptr = cnt + GG;
  int* col     = row_ptr + NN + 2;
  int* hblk    = col + EE;
  int* incl2   = hblk + LEN;
  int* bsum2   = incl2 + LEN;
  int* boff2   = bsum2 + 128;
  int* eoff    = boff2 + 128;
  int2* ebuf   = (int2*)((((uintptr_t)(eoff + LEN)) + 15) & ~(uintptr_t)15);

  hipMemsetAsync(pooled, 0, (GG * 64 + GG) * sizeof(float), stream);

  // bucketed CSR build (once per call; reused by all 4 layers)
  k_bh<<<EB, 256, 0, stream>>>(ei, hblk);
  int nb2 = (LEN + 1023) / 1024;
  k_scan1<<<nb2, 256, 0, stream>>>(hblk, incl2, bsum2, LEN);
  k_scan2<<<1, 64, 0, stream>>>(bsum2, boff2, nb2);
  k_eoff<<<(LEN + 255) / 256, 256, 0, stream>>>(incl2, boff2, hblk, eoff, LEN);
  k_binwrite<<<EB, 256, 0, stream>>>(ei, eoff, ebuf);
  k_bcsr<<<NBUK, 256, 0, stream>>>(ebuf, eoff, row_ptr, col, NN);

  int gg = (NN + 63) / 64;
  int ga = (NN + FB_DST - 1) / FB_DST;  // 32 dsts per block, 128 threads

  // layer 0 (F_IN=16, fp32 input)
  k_gemm_mfma<FIN, float><<<gg, 256, 0, stream>>>(
      x, Wq0, bq0, Wk0, bk0, Wv0, bv0, Ws0, bs0, qh, kh, vh, B0, NN);
  k_fused<<<ga, 128, 0, stream>>>(qh, kh, vh, row_ptr, col, B0, NN);

  // hidden layers (H=64, fp16 h), ping-pong B0 <-> B1
  const __half* hin = B0;
  __half* hout = B1;
  for (int i = 0; i < NHID; i++) {
    k_gemm_mfma<HH, __half><<<gg, 256, 0, stream>>>(
        hin, Wqh + i * 4096, bqh + i * 64,
        Wkh + i * 4096, bkh + i * 64,
        Wvh + i * 4096, bvh + i * 64,
        Wsh + i * 4096, bsh + i * 64,
        qh, kh, vh, hout, NN);
    k_fused<<<ga, 128, 0, stream>>>(qh, kh, vh, row_ptr, col, hout, NN);
    __half* t = (__half*)hin; hin = hout; hout = t;
  }

  k_pool<<<(NN + 63) / 64, 256, 0, stream>>>(hin, batch, pooled, cnt, NN);
  k_out<<<GG, 64, 0, stream>>>(pooled, cnt, Wf, bf, (float*)d_out);
}

// Round 11
// 427.404 us; speedup vs baseline: 1.7410x; 1.0077x over previous
//
#include <hip/hip_runtime.h>
#include <hip/hip_fp16.h>
#include <math.h>
#include <stdint.h>
#include <type_traits>

#define NN   100000
#define EE   1200000
#define GG   128
#define FIN  16
#define HH   64
#define OUTF 5
#define NHID 3

#define CE   4096                       // edges per block in bucket phases
#define EB   ((EE + CE - 1) / CE)       // 293 edge-blocks
#define NBUK ((NN + 511) >> 9)          // 196 buckets of 512 nodes
#define LEN  (NBUK * EB)                // hblk/eoff length

#define SRCMASK 0x03FFFFFFu             // low 26 bits of packed col entry
#define FB_DST 32                       // dsts per fused block

typedef _Float16 f16x8 __attribute__((ext_vector_type(8)));
typedef _Float16 f16x2 __attribute__((ext_vector_type(2)));
typedef float f32x4 __attribute__((ext_vector_type(4)));

#if defined(__has_builtin)
#if __has_builtin(__builtin_amdgcn_fdot2)
#define HAVE_FDOT2 1
#endif
#endif

static __device__ __forceinline__ float dot8_f16(f16x8 a, f16x8 b) {
#ifdef HAVE_FDOT2
  float ds = 0.f;
#pragma unroll
  for (int u = 0; u < 4; u++) {
    f16x2 x = {a[2 * u], a[2 * u + 1]};
    f16x2 y = {b[2 * u], b[2 * u + 1]};
    ds = __builtin_amdgcn_fdot2(x, y, ds, false);
  }
  return ds;
#else
  float ds = 0.f;
#pragma unroll
  for (int u = 0; u < 8; u++) ds += (float)a[u] * (float)b[u];
  return ds;
#endif
}

// ---------------- wave helpers ----------------
static __device__ __forceinline__ float wave_reduce_sum(float p) {
#pragma unroll
  for (int m = 32; m >= 1; m >>= 1) p += __shfl_xor(p, m, 64);
  return p;
}

// ---------------- bucketed CSR build ----------------
__global__ void k_bh(const int* __restrict__ ei, int* __restrict__ hblk) {
  __shared__ int h[NBUK];
  int tid = threadIdx.x, blk = blockIdx.x;
  for (int i = tid; i < NBUK; i += 256) h[i] = 0;
  __syncthreads();
  int base = blk * CE;
  for (int i = tid; i < CE; i += 256) {
    int e = base + i;
    if (e < EE) atomicAdd(&h[ei[EE + e] >> 9], 1);
  }
  __syncthreads();
  for (int i = tid; i < NBUK; i += 256) hblk[i * EB + blk] = h[i];
}

__global__ void k_scan1(const int* __restrict__ in, int* __restrict__ incl,
                        int* __restrict__ bsum, int n) {
  __shared__ int sd[256];
  int t = threadIdx.x, blk = blockIdx.x;
  int base = blk * 1024 + t * 4;
  int v[4];
#pragma unroll
  for (int i = 0; i < 4; i++) v[i] = (base + i < n) ? in[base + i] : 0;
  int s = v[0] + v[1] + v[2] + v[3];
  sd[t] = s;
  __syncthreads();
  for (int off = 1; off < 256; off <<= 1) {
    int x = 0;
    if (t >= off) x = sd[t - off];
    __syncthreads();
    if (t >= off) sd[t] += x;
    __syncthreads();
  }
  int run = sd[t] - s;
#pragma unroll
  for (int i = 0; i < 4; i++) {
    run += v[i];
    if (base + i < n) incl[base + i] = run;
  }
  if (t == 255) bsum[blk] = sd[255];
}

__global__ void k_scan2(const int* __restrict__ bsum, int* __restrict__ boff, int nb) {
  if (threadIdx.x == 0 && blockIdx.x == 0) {
    int run = 0;
    for (int i = 0; i < nb; i++) { boff[i] = run; run += bsum[i]; }
  }
}

__global__ void k_eoff(const int* __restrict__ incl, const int* __restrict__ boff,
                       const int* __restrict__ hblk, int* __restrict__ eoff, int n) {
  int t = blockIdx.x * blockDim.x + threadIdx.x;
  if (t < n) eoff[t] = incl[t] + boff[t / 1024] - hblk[t];
}

__global__ void k_binwrite(const int* __restrict__ ei, const int* __restrict__ eoff,
                           int2* __restrict__ ebuf) {
  __shared__ int cur[NBUK];
  int tid = threadIdx.x, blk = blockIdx.x;
  for (int i = tid; i < NBUK; i += 256) cur[i] = eoff[i * EB + blk];
  __syncthreads();
  int base = blk * CE;
  for (int i = tid; i < CE; i += 256) {
    int e = base + i;
    if (e < EE) {
      int d = ei[EE + e];
      int s = ei[e];
      int p = atomicAdd(&cur[d >> 9], 1);
      ebuf[p] = make_int2(s, d);
    }
  }
}

// merged bdeg2 + binscatter: histogram -> scan -> row_ptr -> cursors ->
// scatter col. col entry packs dst-mod-64 into bits 26..31 (unused by the
// fused kernel, masked off harmlessly); src (<2^26) in low bits.
__global__ void k_bcsr(const int2* __restrict__ ebuf, const int* __restrict__ eoff,
                       int* __restrict__ row_ptr, int* __restrict__ col, int n) {
  __shared__ int dl[512];
  __shared__ int ps[256];
  int b = blockIdx.x, tid = threadIdx.x;
  int d0 = b << 9;
  dl[tid] = 0; dl[tid + 256] = 0;
  __syncthreads();
  int s0 = eoff[b * EB];
  int s1 = (b + 1 < NBUK) ? eoff[(b + 1) * EB] : EE;
  for (int e = s0 + tid; e < s1; e += 256) atomicAdd(&dl[ebuf[e].y - d0], 1);
  __syncthreads();
  int a0 = dl[2 * tid], a1 = dl[2 * tid + 1];
  ps[tid] = a0 + a1;
  __syncthreads();
  for (int off = 1; off < 256; off <<= 1) {
    int x = 0;
    if (tid >= off) x = ps[tid - off];
    __syncthreads();
    if (tid >= off) ps[tid] += x;
    __syncthreads();
  }
  int epair = ps[tid] - (a0 + a1);     // exclusive prefix of this pair
  int r0 = s0 + epair;
  int r1 = r0 + a0;
  int i0 = d0 + 2 * tid;
  if (i0 <= n) row_ptr[i0] = r0;       // covers row_ptr[n] = EE
  if (i0 + 1 <= n) row_ptr[i0 + 1] = r1;
  __syncthreads();
  dl[2 * tid] = r0;                    // reuse histogram LDS as cursors
  dl[2 * tid + 1] = r1;
  __syncthreads();
  for (int e = s0 + tid; e < s1; e += 256) {
    int2 sd = ebuf[e];
    int p = atomicAdd(&dl[sd.y - d0], 1);
    col[p] = (int)(((unsigned)sd.x) | (((unsigned)sd.y & 63u) << 26));
  }
}

// ---------------- projections via MFMA (R25: per-wave LDS out-staging) ------
// Core (stage/weights/MFMA) is R20-proven. Epilogue: after the one barrier
// that ends xs reads, each wave owns a PRIVATE 16x68 LDS region (no
// round-robin, no extra barriers — R22's mistake). Per ms-tile: write acc
// sub-tile (conflict-free bank mapping), read back as f16x8, store 1KB
// fully-contiguous per instruction. Replaces 64x scalar 2B global stores
// per lane (4 scattered 32B fragments per store instruction).
template <int F, typename TIN>
__global__ __launch_bounds__(256) void k_gemm_mfma(
    const TIN* __restrict__ X,
    const float* __restrict__ Wq, const float* __restrict__ bq,
    const float* __restrict__ Wk, const float* __restrict__ bk,
    const float* __restrict__ Wv, const float* __restrict__ bv,
    const float* __restrict__ Ws, const float* __restrict__ bs,
    __half* __restrict__ qh, __half* __restrict__ kh, __half* __restrict__ vh,
    __half* __restrict__ Bh, int n) {
  constexpr int KH = (F + 31) / 32;
  constexpr int S = KH * 32 + 8;
  constexpr int STG = 64 * S;
  constexpr int OUTL = 4 * 16 * 68;        // 4 waves x private 16x68
  constexpr int LSZ = (STG > OUTL) ? STG : OUTL;
  __shared__ _Float16 xs[LSZ];
  int tid = threadIdx.x;
  int lane = tid & 63;
  int wv = tid >> 6;
  int quad = lane >> 4;
  int li = lane & 15;
  int node0 = blockIdx.x * 64;

  if constexpr (std::is_same<TIN, float>::value) {
    constexpr int F4 = F / 4;
    constexpr int CNT = 64 * F4 / 256;
#pragma unroll
    for (int i = 0; i < CNT; i++) {
      int idx = tid + i * 256;
      int nd = idx / F4;
      int kb = (idx % F4) * 4;
      float4 p;
      if (node0 + nd < n) p = *(const float4*)(X + (size_t)(node0 + nd) * F + kb);
      else p = make_float4(0.f, 0.f, 0.f, 0.f);
      _Float16* d = xs + nd * S + kb;
      d[0] = (_Float16)p.x; d[1] = (_Float16)p.y;
      d[2] = (_Float16)p.z; d[3] = (_Float16)p.w;
    }
    if (F == 16) {  // zero-pad k in [16,32)
      int nd = tid >> 2;
      int kb = 16 + (tid & 3) * 4;
      _Float16* d = xs + nd * S + kb;
      d[0] = 0; d[1] = 0; d[2] = 0; d[3] = 0;
    }
  } else {
    constexpr int F8 = F / 8;
    constexpr int CNT = 64 * F8 / 256;
#pragma unroll
    for (int i = 0; i < CNT; i++) {
      int idx = tid + i * 256;
      int nd = idx / F8;
      int kb = (idx % F8) * 8;
      f16x8 p = {};
      if (node0 + nd < n)
        p = *(const f16x8*)((const _Float16*)X + (size_t)(node0 + nd) * F + kb);
      *(f16x8*)(xs + nd * S + kb) = p;
    }
  }

  const float* W; const float* bias;
  if (wv == 0)      { W = Wq; bias = bq; }
  else if (wv == 1) { W = Wk; bias = bk; }
  else if (wv == 2) { W = Wv; bias = bv; }
  else              { W = Ws; bias = bs; }

  f16x8 bf[4][KH];
#pragma unroll
  for (int ns = 0; ns < 4; ns++)
#pragma unroll
    for (int kh2 = 0; kh2 < KH; kh2++)
#pragma unroll
      for (int j = 0; j < 8; j++) {
        int kidx = kh2 * 32 + quad * 8 + j;
        bf[ns][kh2][j] = (kidx < F)
            ? (_Float16)W[(size_t)kidx * 64 + ns * 16 + li] : (_Float16)0.f;
      }
  float blv[4];
#pragma unroll
  for (int ns = 0; ns < 4; ns++) blv[ns] = bias[ns * 16 + li];

  __syncthreads();

  f16x8 af[4][KH];
#pragma unroll
  for (int ms = 0; ms < 4; ms++)
#pragma unroll
    for (int kh2 = 0; kh2 < KH; kh2++)
      af[ms][kh2] = *(const f16x8*)(xs + (ms * 16 + li) * S + kh2 * 32 + quad * 8);

  f32x4 acc[4][4];
#pragma unroll
  for (int ms = 0; ms < 4; ms++)
#pragma unroll
    for (int ns = 0; ns < 4; ns++) {
      float b = blv[ns];
      acc[ms][ns] = (f32x4){b, b, b, b};
    }
#pragma unroll
  for (int kh2 = 0; kh2 < KH; kh2++)
#pragma unroll
    for (int ms = 0; ms < 4; ms++)
#pragma unroll
      for (int ns = 0; ns < 4; ns++)
        acc[ms][ns] = __builtin_amdgcn_mfma_f32_16x16x32_f16(
            af[ms][kh2], bf[ns][kh2], acc[ms][ns], 0, 0, 0);

  __syncthreads();   // end of xs (af) reads; out-staging regions now safe

  __half* outh = (wv == 0) ? qh : (wv == 1) ? kh : (wv == 2) ? vh : Bh;
  _Float16* ob = xs + wv * (16 * 68);   // per-wave private region
#pragma unroll
  for (int ms = 0; ms < 4; ms++) {
    // write this wave's 16x64 sub-tile (rows quad*4+r, cols ns*16+li)
#pragma unroll
    for (int ns = 0; ns < 4; ns++)
#pragma unroll
      for (int r = 0; r < 4; r++)
        ob[(quad * 4 + r) * 68 + ns * 16 + li] = (_Float16)acc[ms][ns][r];
    // read back coalesced and store 1KB-contiguous (within-wave lgkmcnt
    // ordering is compiler-inserted; regions are wave-private -> no barrier)
#pragma unroll
    for (int it = 0; it < 2; it++) {
      int c = lane + it * 64;
      int row = c >> 3, j = c & 7;
      int node = node0 + ms * 16 + row;
      if (node < n)
        *(f16x8*)((_Float16*)outh + (size_t)node * 64 + j * 8) =
            *(const f16x8*)(ob + row * 68 + j * 8);
    }
  }
}

// ---------------- fused attention, phase-split + register acc (R24-proven) --
__global__ __launch_bounds__(128) void k_fused(
    const __half* __restrict__ qh, const __half* __restrict__ kh,
    const __half* __restrict__ vh, const int* __restrict__ row_ptr,
    const int* __restrict__ col, __half* __restrict__ Bh, int n) {
  __shared__ int ws[1024];
  __shared__ float pw[1024];
  __shared__ int rpl[FB_DST + 1];
  int tid = threadIdx.x;
  int d0 = blockIdx.x * FB_DST;
  int ndst = n - d0; if (ndst > FB_DST) ndst = FB_DST;

  if (tid < FB_DST + 1) {
    int dd = d0 + tid; if (dd > n) dd = n;
    rpl[tid] = row_ptr[dd];
  }
  __syncthreads();
  int e0 = rpl[0], e1 = rpl[ndst];

  int g = tid >> 3, aj = tid & 7;     // 16 groups x 8 lanes

  f16x8 qv[2] = {};
  float acc[2][8];
  float den[2];
#pragma unroll
  for (int t = 0; t < 2; t++) {
    den[t] = 0.f;
#pragma unroll
    for (int u = 0; u < 8; u++) acc[t][u] = 0.f;
    int dl = 2 * g + t;
    if (dl < ndst)
      qv[t] = *(const f16x8*)((const _Float16*)qh + (size_t)(d0 + dl) * 64 + aj * 8);
  }

  for (int c0 = e0; c0 < e1; c0 += 1024) {
    int cn = e1 - c0; if (cn > 1024) cn = 1024;
#pragma unroll
    for (int s = 0; s < 8; s++) {      // stage col chunk, coalesced
      int i = tid + s * 128;
      if (i < cn) ws[i] = col[c0 + i];
    }
    __syncthreads();

    // ---- K-pass: k-gathers only -> pe, den, pw ----
#pragma unroll
    for (int t = 0; t < 2; t++) {
      int dl = 2 * g + t;
      if (dl < ndst) {
        int lo = rpl[dl];     if (lo < c0) lo = c0;
        int hi = rpl[dl + 1]; int ce = c0 + cn; if (hi > ce) hi = ce;
        int i = lo - c0, iend = hi - c0;
        for (; i + 2 <= iend; i += 2) {
          int s0 = ws[i] & (int)SRCMASK;
          int s1 = ws[i + 1] & (int)SRCMASK;
          f16x8 k0 = *(const f16x8*)((const _Float16*)kh + (size_t)s0 * 64 + aj * 8);
          f16x8 k1 = *(const f16x8*)((const _Float16*)kh + (size_t)s1 * 64 + aj * 8);
          float da = dot8_f16(qv[t], k0);
          float db = dot8_f16(qv[t], k1);
          da += __shfl_xor(da, 1, 64); db += __shfl_xor(db, 1, 64);
          da += __shfl_xor(da, 2, 64); db += __shfl_xor(db, 2, 64);
          da += __shfl_xor(da, 4, 64); db += __shfl_xor(db, 4, 64);
          float pa = __expf(fminf(da * 0.125f, 60.f));   // 1/sqrt(64)
          float pb = __expf(fminf(db * 0.125f, 60.f));
          den[t] += pa + pb;
          if (aj == 0) { pw[i] = pa; pw[i + 1] = pb; }
        }
        if (i < iend) {
          int s0 = ws[i] & (int)SRCMASK;
          f16x8 k0 = *(const f16x8*)((const _Float16*)kh + (size_t)s0 * 64 + aj * 8);
          float da = dot8_f16(qv[t], k0);
          da += __shfl_xor(da, 1, 64);
          da += __shfl_xor(da, 2, 64);
          da += __shfl_xor(da, 4, 64);
          float pa = __expf(fminf(da * 0.125f, 60.f));
          den[t] += pa;
          if (aj == 0) pw[i] = pa;
        }
      }
    }
    __syncthreads();   // phase the gather streams (locality, not correctness)

    // ---- V-pass: v-gathers only; pw broadcast reads; fma into registers ----
#pragma unroll
    for (int t = 0; t < 2; t++) {
      int dl = 2 * g + t;
      if (dl < ndst) {
        int lo = rpl[dl];     if (lo < c0) lo = c0;
        int hi = rpl[dl + 1]; int ce = c0 + cn; if (hi > ce) hi = ce;
        int i = lo - c0, iend = hi - c0;
        for (; i + 2 <= iend; i += 2) {
          int s0 = ws[i] & (int)SRCMASK;
          int s1 = ws[i + 1] & (int)SRCMASK;
          float pa = pw[i], pb = pw[i + 1];
          f16x8 v0 = *(const f16x8*)((const _Float16*)vh + (size_t)s0 * 64 + aj * 8);
          f16x8 v1 = *(const f16x8*)((const _Float16*)vh + (size_t)s1 * 64 + aj * 8);
#pragma unroll
          for (int u = 0; u < 8; u++) {
            acc[t][u] = fmaf(pa, (float)v0[u], acc[t][u]);
            acc[t][u] = fmaf(pb, (float)v1[u], acc[t][u]);
          }
        }
        if (i < iend) {
          int s0 = ws[i] & (int)SRCMASK;
          float pa = pw[i];
          f16x8 v0 = *(const f16x8*)((const _Float16*)vh + (size_t)s0 * 64 + aj * 8);
#pragma unroll
          for (int u = 0; u < 8; u++)
            acc[t][u] = fmaf(pa, (float)v0[u], acc[t][u]);
        }
      }
    }
    __syncthreads();   // before next chunk overwrites ws/pw
  }

  // write out (B pre-holds the skip term); 8 lanes cover one dst row
#pragma unroll
  for (int t = 0; t < 2; t++) {
    int dl = 2 * g + t;
    if (dl < ndst) {
      _Float16* bp = (_Float16*)Bh + (size_t)(d0 + dl) * 64 + aj * 8;
      f16x8 old = *(const f16x8*)bp;
      float inv = 1.f / (den[t] + 1e-16f);
      f16x8 o;
#pragma unroll
      for (int u = 0; u < 8; u++)
        o[u] = (_Float16)((float)old[u] + acc[t][u] * inv);
      *(f16x8*)bp = o;
    }
  }
}

// ---------------- pooling ----------------
__global__ __launch_bounds__(256) void k_pool(
    const __half* __restrict__ H, const int* __restrict__ batch,
    float* __restrict__ pooled, int* __restrict__ cnt, int n) {
  int lane = threadIdx.x & 63;
  int w = threadIdx.x >> 6;
  int n0 = blockIdx.x * 64 + w * 16;
  float acc = 0.f;
  int cur = -1, nc = 0;
  for (int i = 0; i < 16; i++) {
    int node = n0 + i;
    if (node >= n) break;
    int g = batch[node];
    if (g != cur) {
      if (cur >= 0) {
        atomicAdd(&pooled[cur * 64 + lane], acc);
        if (lane == 0) atomicAdd(&cnt[cur], nc);
      }
      cur = g;
      acc = 0.f;
      nc = 0;
    }
    acc += __half2float(H[(size_t)node * 64 + lane]);
    nc++;
  }
  if (cur >= 0) {
    atomicAdd(&pooled[cur * 64 + lane], acc);
    if (lane == 0) atomicAdd(&cnt[cur], nc);
  }
}

__global__ void k_out(const float* __restrict__ pooled, const int* __restrict__ cnt,
                      const float* __restrict__ Wf, const float* __restrict__ bf,
                      float* __restrict__ out) {
  int g = blockIdx.x;
  int lane = threadIdx.x;
  int c = cnt[g];
  float cf = (float)(c > 1 ? c : 1);
  float mean = pooled[g * 64 + lane] / cf;
#pragma unroll
  for (int o = 0; o < OUTF; o++) {
    float p = wave_reduce_sum(mean * Wf[lane * OUTF + o]);
    if (lane == 0) out[g * OUTF + o] = p + bf[o];
  }
}

// ---------------- launch ----------------
extern "C" void kernel_launch(void* const* d_in, const int* in_sizes, int n_in,
                              void* d_out, int out_size, void* d_ws, size_t ws_size,
                              hipStream_t stream) {
  const float* x   = (const float*)d_in[0];
  const int* ei    = (const int*)d_in[1];
  const int* batch = (const int*)d_in[2];
  const float *Wq0 = (const float*)d_in[3],  *bq0 = (const float*)d_in[4];
  const float *Wk0 = (const float*)d_in[5],  *bk0 = (const float*)d_in[6];
  const float *Wv0 = (const float*)d_in[7],  *bv0 = (const float*)d_in[8];
  const float *Ws0 = (const float*)d_in[9],  *bs0 = (const float*)d_in[10];
  const float *Wqh = (const float*)d_in[11], *bqh = (const float*)d_in[12];
  const float *Wkh = (const float*)d_in[13], *bkh = (const float*)d_in[14];
  const float *Wvh = (const float*)d_in[15], *bvh = (const float*)d_in[16];
  const float *Wsh = (const float*)d_in[17], *bsh = (const float*)d_in[18];
  const float *Wf  = (const float*)d_in[19], *bf  = (const float*)d_in[20];

  __half* qh = (__half*)d_ws;
  __half* kh = qh + (size_t)NN * 64;
  __half* vh = kh + (size_t)NN * 64;
  __half* B0 = vh + (size_t)NN * 64;
  __half* B1 = B0 + (size_t)NN * 64;
  float* pooled = (float*)(B1 + (size_t)NN * 64);
  int* cnt     = (int*)(pooled + GG * 64);
  int* row_ptr = cnt + GG;
  int* col     = row_ptr + NN + 2;
  int* hblk    = col + EE;
  int* incl2   = hblk + LEN;
  int* bsum2   = incl2 + LEN;
  int* boff2   = bsum2 + 128;
  int* eoff    = boff2 + 128;
  int2* ebuf   = (int2*)((((uintptr_t)(eoff + LEN)) + 15) & ~(uintptr_t)15);

  hipMemsetAsync(pooled, 0, (GG * 64 + GG) * sizeof(float), stream);

  // bucketed CSR build (once per call; reused by all 4 layers)
  k_bh<<<EB, 256, 0, stream>>>(ei, hblk);
  int nb2 = (LEN + 1023) / 1024;
  k_scan1<<<nb2, 256, 0, stream>>>(hblk, incl2, bsum2, LEN);
  k_scan2<<<1, 64, 0, stream>>>(bsum2, boff2, nb2);
  k_eoff<<<(LEN + 255) / 256, 256, 0, stream>>>(incl2, boff2, hblk, eoff, LEN);
  k_binwrite<<<EB, 256, 0, stream>>>(ei, eoff, ebuf);
  k_bcsr<<<NBUK, 256, 0, stream>>>(ebuf, eoff, row_ptr, col, NN);

  int gg = (NN + 63) / 64;
  int ga = (NN + FB_DST - 1) / FB_DST;  // 32 dsts per block, 128 threads

  // layer 0 (F_IN=16, fp32 input)
  k_gemm_mfma<FIN, float><<<gg, 256, 0, stream>>>(
      x, Wq0, bq0, Wk0, bk0, Wv0, bv0, Ws0, bs0, qh, kh, vh, B0, NN);
  k_fused<<<ga, 128, 0, stream>>>(qh, kh, vh, row_ptr, col, B0, NN);

  // hidden layers (H=64, fp16 h), ping-pong B0 <-> B1
  const __half* hin = B0;
  __half* hout = B1;
  for (int i = 0; i < NHID; i++) {
    k_gemm_mfma<HH, __half><<<gg, 256, 0, stream>>>(
        hin, Wqh + i * 4096, bqh + i * 64,
        Wkh + i * 4096, bkh + i * 64,
        Wvh + i * 4096, bvh + i * 64,
        Wsh + i * 4096, bsh + i * 64,
        qh, kh, vh, hout, NN);
    k_fused<<<ga, 128, 0, stream>>>(qh, kh, vh, row_ptr, col, hout, NN);
    __half* t = (__half*)hin; hin = hout; hout = t;
  }

  k_pool<<<(NN + 63) / 64, 256, 0, stream>>>(hin, batch, pooled, cnt, NN);
  k_out<<<GG, 64, 0, stream>>>(pooled, cnt, Wf, bf, (float*)d_out);
}